// Round 3
// baseline (42579.520 us; speedup 1.0000x reference)
//
#include <hip/hip_runtime.h>
#include <hip/hip_bf16.h>

typedef _Float16 h2 __attribute__((ext_vector_type(2)));
union U32H2 { unsigned u; h2 h; };

__device__ __forceinline__ h2 uh(unsigned u){ U32H2 c; c.u=u; return c.h; }
__device__ __forceinline__ unsigned pk(float a, float b){
  U32H2 c; c.h = h2{(_Float16)a, (_Float16)b}; return c.u;
}
#define RCPF(x) __builtin_amdgcn_rcpf(x)

__device__ __forceinline__ float DOT2(unsigned a, unsigned b, float acc){
#if __has_builtin(__builtin_amdgcn_fdot2)
  return __builtin_amdgcn_fdot2(uh(a), uh(b), acc, false);
#else
  h2 x = uh(a), y = uh(b);
  acc = fmaf((float)x[0], (float)y[0], acc);
  return fmaf((float)x[1], (float)y[1], acc);
#endif
}
__device__ __forceinline__ float sigm(float x){ return RCPF(1.0f + __expf(-x)); }
__device__ __forceinline__ float ftanh(float x){ return 1.0f - 2.0f*RCPF(1.0f + __expf(x + x)); }
__device__ __forceinline__ float wredmax(float v){
  #pragma unroll
  for(int o=1;o<64;o<<=1) v = fmaxf(v, __shfl_xor(v,o,64));
  return v;
}
__device__ __forceinline__ float wredsum(float v){
  #pragma unroll
  for(int o=1;o<64;o<<=1) v += __shfl_xor(v,o,64);
  return v;
}

// ---------------- one-time weight folds (f32, GEMM inputs) ----------------
__global__ void k_fold(const float* __restrict__ Wp, const float* __restrict__ Wq,
                       const float* __restrict__ Wg,
                       float* __restrict__ WpT, float* __restrict__ WqT,
                       float* __restrict__ WgupT)
{
  int i0 = blockIdx.x*blockDim.x+threadIdx.x;
  int st = gridDim.x*blockDim.x;
  for(int o=i0;o<512*150;o+=st){ int h=o%150, i=o/150;
    WpT[o]=Wp[h*1024+i]+Wp[h*1024+512+i];
    WqT[o]=Wq[h*1024+i]+Wq[h*1024+512+i]; }
  for(int o=i0;o<512*1024;o+=st){ int i=o&511, j=o>>9;
    size_t rb=(size_t)(1024+j)*2048;
    WgupT[(size_t)i*1024+j]=Wg[rb+i]+Wg[rb+512+i]; }
}

// ---------------- f16-pair weight layouts for the persistent kernel ----------------
__global__ void k_fold2(const float* __restrict__ Wg, const float* __restrict__ Wih,
                        const float* __restrict__ Whh, const float* __restrict__ Wv,
                        _Float16* __restrict__ WgcP, _Float16* __restrict__ WihP,
                        unsigned* __restrict__ WhhU, unsigned* __restrict__ WvU)
{
  int i0 = blockIdx.x*blockDim.x+threadIdx.x;
  int st = gridDim.x*blockDim.x;
  // WgcP[(i/8)*1024 + j][i%8]: folded Wg rows 1024..2047, cols (1024+i)+(1536+i)
  for(int o=i0;o<512*1024;o+=st){ int i=o&511, j=o>>9;
    size_t rb=(size_t)(1024+j)*2048;
    WgcP[((size_t)(i>>3)*1024 + j)*8 + (i&7)] = (_Float16)(Wg[rb+1024+i]+Wg[rb+1536+i]); }
  // WihP[(j/8)*450 + k][j%8]
  for(int o=i0;o<450*1024;o+=st){ int j=o&1023, k=o>>10;
    WihP[((size_t)(j>>3)*450 + k)*8 + (j&7)] = (_Float16)Wih[(size_t)k*1024 + j]; }
  // WhhU[p*450+k] = pair (Whh[k,2p], Whh[k,2p+1]), zero-padded past 150
  for(int o=i0;o<76*450;o+=st){ int k=o%450, p=o/450;
    float x = (2*p<150)? Whh[k*150+2*p] : 0.f;
    float y = (2*p+1<150)? Whh[k*150+2*p+1] : 0.f;
    WhhU[p*450+k] = pk(x,y); }
  // WvU[p*152+h] = pair (Wv[h,2p], Wv[h,2p+1])
  for(int o=i0;o<76*150;o+=st){ int h=o%150, p=o/150;
    float x = (2*p<150)? Wv[h*150+2*p] : 0.f;
    float y = (2*p+1<150)? Wv[h*150+2*p+1] : 0.f;
    WvU[p*152+h] = pk(x,y); }
}

// ---------------- precompute GEMMs, f16 outputs ----------------
// C[m][n] = sum_k A[m*512+k]*WT[k*N+n], m-tile = 32 rows.
// MODE 0: Wuph[(mt*32+m)*152+n]      (m=b, mt=t, N=150)
// MODE 3: WqUqh[(m*256+mt)*152+n]    (m=b, mt=q, N=150)
// MODE 4: Guph[(m*512+mt)*1024+n]    (m=b, mt=t, N=1024)
template<int MODE>
__global__ __launch_bounds__(256) void k_gemm(const float* __restrict__ A,
   const float* __restrict__ WT, _Float16* __restrict__ oH, int N)
{
  __shared__ float Al[32*512];
  int mt=blockIdx.x, nt=blockIdx.y, tid=threadIdx.x;
  const float* Ab = A + (size_t)mt*16384;
  for(int o=tid;o<4096;o+=256) ((float4*)Al)[o]=((const float4*)Ab)[o];
  __syncthreads();
  int n = nt*256+tid;
  if(n>=N) return;
  float acc[32];
  #pragma unroll
  for(int m=0;m<32;m++) acc[m]=0.f;
  const float* wp = WT + n;
  #pragma unroll 2
  for(int k=0;k<512;k+=2){
    float w0 = wp[(size_t)k*N], w1 = wp[(size_t)(k+1)*N];
    #pragma unroll
    for(int m=0;m<32;m++) acc[m]=fmaf(w0, Al[m*512+k], acc[m]);
    #pragma unroll
    for(int m=0;m<32;m++) acc[m]=fmaf(w1, Al[m*512+k+1], acc[m]);
  }
  if(MODE==0){
    #pragma unroll
    for(int m=0;m<32;m++) oH[((size_t)mt*32+m)*152 + n] = (_Float16)acc[m];
  } else if(MODE==3){
    #pragma unroll
    for(int m=0;m<32;m++) oH[((size_t)m*256+mt)*152 + n] = (_Float16)acc[m];
  } else {
    #pragma unroll
    for(int m=0;m<32;m++) oH[((size_t)m*512+mt)*1024 + n] = (_Float16)acc[m];
  }
}

// ---------------- per-batch persistent kernel: 32 blocks x 1024, zero inter-block sync ----------------
struct __align__(16) SM {
  unsigned ccp[256];    // cc as f16 pairs
  unsigned cp_[512];    // c_ as f16 pairs
  unsigned vp[76];      // v as f16 pairs
  float v_[152];
  float Vl[152];
  float w2_[152];
  float s_[256];
  float a_[256];
  float ccf[512];
  float gi_[452];
  float gh_[452];
  float bi_[452];
  float bh_[452];
};

__global__ __launch_bounds__(1024,4) void persist(
  const float* __restrict__ uq, const float* __restrict__ v0,
  const float* __restrict__ Vin,
  const float* __restrict__ bih, const float* __restrict__ bhh,
  const _Float16* __restrict__ Wuph, const _Float16* __restrict__ WqUqh,
  const uint4* __restrict__ WgcP4, const uint4* __restrict__ WihP4,
  const unsigned* __restrict__ WhhU, const unsigned* __restrict__ WvU,
  const _Float16* __restrict__ Guph,
  float* __restrict__ dout)
{
  extern __shared__ char smraw[];
  SM& S = *reinterpret_cast<SM*>(smraw);
  const int tid = threadIdx.x;
  const int b = blockIdx.x;

  // prologue
  for(int o=tid;o<152;o+=1024){
    S.v_[o] = (o<150)? v0[b*150+o] : 0.f;
    S.Vl[o] = (o<150)? Vin[b*150+o] : 0.f;
  }
  for(int o=tid;o<452;o+=1024){
    S.bi_[o] = (o<450)? bih[o] : 0.f;
    S.bh_[o] = (o<450)? bhh[o] : 0.f;
  }
  __syncthreads();
  if(tid<76) S.vp[tid] = pk(S.v_[2*tid], S.v_[2*tid+1]);
  __syncthreads();

  for(int t=0; t<512; ++t){
    // ---- A: w2[h] = Wup[t,b,h] + (Wv . v)[h] ----
    if(tid<608){
      int h=tid>>2, qd=tid&3;
      float acc=0.f;
      if(h<150){
        int p0=qd*19;
        #pragma unroll
        for(int p=p0;p<p0+19;p++) acc = DOT2(WvU[p*152+h], S.vp[p], acc);
      }
      acc += __shfl_xor(acc,1,64); acc += __shfl_xor(acc,2,64);
      if(h<150 && qd==0)
        S.w2_[h] = acc + (float)Wuph[((size_t)t*32+b)*152 + h];
    }
    __syncthreads();

    // ---- B: s[q] = sum_h V[h] * tanh(w2[h] + WqUq[b,q,h]) ----
    {
      int q=tid>>2, hq=tid&3;
      int h0=hq*38, h1 = (h0+38>150)? 150 : h0+38;
      const unsigned* wq = (const unsigned*)WqUqh + ((size_t)b*256+q)*76;
      float acc=0.f;
      #pragma unroll 4
      for(int h=h0; h<h1; h+=2){
        h2 wp = uh(wq[h>>1]);
        float x0 = S.w2_[h]   + (float)wp[0];
        float x1 = S.w2_[h+1] + (float)wp[1];
        float t0 = ftanh(x0);
        float t1 = ftanh(x1);
        acc = fmaf(S.Vl[h],   t0, acc);
        acc = fmaf(S.Vl[h+1], t1, acc);
      }
      acc += __shfl_xor(acc,1,64); acc += __shfl_xor(acc,2,64);
      if(hq==0) S.s_[q] = acc;
    }
    __syncthreads();

    // ---- C1: softmax over 256 (single wave) ----
    if(tid<64){
      float x0=S.s_[tid], x1=S.s_[tid+64], x2=S.s_[tid+128], x3=S.s_[tid+192];
      float mx = wredmax(fmaxf(fmaxf(x0,x1),fmaxf(x2,x3)));
      float e0=__expf(x0-mx), e1=__expf(x1-mx), e2=__expf(x2-mx), e3=__expf(x3-mx);
      float r = RCPF(wredsum(e0+e1+e2+e3));
      S.a_[tid]=e0*r; S.a_[tid+64]=e1*r; S.a_[tid+128]=e2*r; S.a_[tid+192]=e3*r;
    }
    __syncthreads();

    // ---- C2: cc[i] = sum_q a[q]*uq[q,b,i] ----
    {
      int i2=tid>>2, qq=tid&3;
      float a0=0.f, a1=0.f;
      const float2* uqp = (const float2*)uq + ((size_t)(qq*64)*32+b)*256 + i2;
      #pragma unroll 4
      for(int k=0;k<64;k++){
        float av = S.a_[qq*64+k];
        float2 u = uqp[(size_t)k*8192];
        a0 = fmaf(av,u.x,a0); a1 = fmaf(av,u.y,a1);
      }
      a0 += __shfl_xor(a0,1,64); a1 += __shfl_xor(a1,1,64);
      a0 += __shfl_xor(a0,2,64); a1 += __shfl_xor(a1,2,64);
      if(qq==0){ S.ccf[2*i2]=a0; S.ccf[2*i2+1]=a1; S.ccp[i2]=pk(a0,a1); }
    }
    __syncthreads();

    // ---- D: Gc[j] = Wgc[j,:].cc ; gate; c_[j] = sigm(Gc+Gup)*cc[j&511] ----
    {
      int jq=tid>>2, iq=tid&3;
      float acc[4]={0.f,0.f,0.f,0.f};
      #pragma unroll 2
      for(int c8=iq*16; c8<iq*16+16; ++c8){
        uint4 cp = *((const uint4*)&S.ccp[c8*4]);
        const uint4* wr = WgcP4 + (size_t)c8*1024 + jq;
        #pragma unroll
        for(int m=0;m<4;m++){
          uint4 w = wr[(size_t)m*256];
          acc[m]=DOT2(w.x,cp.x,acc[m]); acc[m]=DOT2(w.y,cp.y,acc[m]);
          acc[m]=DOT2(w.z,cp.z,acc[m]); acc[m]=DOT2(w.w,cp.w,acc[m]);
        }
      }
      #pragma unroll
      for(int m=0;m<4;m++){ acc[m]+=__shfl_xor(acc[m],1,64); acc[m]+=__shfl_xor(acc[m],2,64); }
      float cv[4]={0.f,0.f,0.f,0.f};
      if(iq==0){
        #pragma unroll
        for(int m=0;m<4;m++){
          int j = jq + 256*m;
          float g = sigm(acc[m] + (float)Guph[((size_t)b*512+t)*1024 + j]);
          cv[m] = g * S.ccf[j&511];
        }
      }
      #pragma unroll
      for(int m=0;m<4;m++){
        float o = __shfl_xor(cv[m],4,64);
        if(iq==0 && (jq&1)==0) S.cp_[(jq>>1) + 128*m] = pk(cv[m], o);
      }
    }
    __syncthreads();

    // ---- E: gi[k] = Wih[k,:].c_ + bih ; gh[k] = Whh[k,:].v + bhh ----
    if((tid>>1)<450){
      int k=tid>>1, jh=tid&1;
      float acc=0.f;
      const uint4* wr = WihP4 + (size_t)(jh*64)*450 + k;
      #pragma unroll 2
      for(int c8=0;c8<64;c8++){
        uint4 cp = *((const uint4*)&S.cp_[(jh*64+c8)*4]);
        uint4 w = wr[(size_t)c8*450];
        acc=DOT2(w.x,cp.x,acc); acc=DOT2(w.y,cp.y,acc);
        acc=DOT2(w.z,cp.z,acc); acc=DOT2(w.w,cp.w,acc);
      }
      float ah=0.f;
      const unsigned* wh = WhhU + k;
      #pragma unroll 2
      for(int p=jh*38; p<jh*38+38; p++) ah = DOT2(wh[(size_t)p*450], S.vp[p], ah);
      acc += __shfl_xor(acc,1,64);
      ah  += __shfl_xor(ah,1,64);
      if(jh==0){ S.gi_[k] = acc + S.bi_[k]; S.gh_[k] = ah + S.bh_[k]; }
    }
    __syncthreads();

    // ---- F: GRU finalize, write v_{t+1} and dout[t] ----
    if(tid<75){
      float vn0, vn1;
      #pragma unroll
      for(int d=0;d<2;d++){
        int h = 2*tid + d;
        float rg = sigm(S.gi_[h]     + S.gh_[h]);
        float zg = sigm(S.gi_[150+h] + S.gh_[150+h]);
        float ng = ftanh(S.gi_[300+h] + rg*S.gh_[300+h]);
        float vn = fmaf(zg, S.v_[h]-ng, ng);
        if(d==0) vn0=vn; else vn1=vn;
      }
      S.v_[2*tid]=vn0; S.v_[2*tid+1]=vn1;
      S.vp[tid]=pk(vn0,vn1);
      float2* dp = (float2*)0; (void)dp;
      dout[((size_t)t*32+b)*150 + 2*tid]   = vn0;
      dout[((size_t)t*32+b)*150 + 2*tid+1] = vn1;
    }
    __syncthreads();
  }
}

// ---------------- host ----------------
extern "C" void kernel_launch(void* const* d_in, const int* in_sizes, int n_in,
                              void* d_out, int out_size, void* d_ws, size_t ws_size,
                              hipStream_t stream)
{
  const float* up  = (const float*)d_in[0];
  const float* uq  = (const float*)d_in[1];
  const float* v0  = (const float*)d_in[2];
  const float* Vm  = (const float*)d_in[3];
  const float* Wp  = (const float*)d_in[4];
  const float* Wq  = (const float*)d_in[5];
  const float* Wv  = (const float*)d_in[6];
  const float* Wg  = (const float*)d_in[7];
  const float* W_ih= (const float*)d_in[8];
  const float* W_hh= (const float*)d_in[9];
  const float* b_ih= (const float*)d_in[10];
  const float* b_hh= (const float*)d_in[11];
  float* dout = (float*)d_out;
  char* wsb = (char*)d_ws;

  size_t off = 0;
  auto alloc = [&](size_t bytes)->size_t{ size_t r = off; off = (off + bytes + 255) & ~(size_t)255; return r; };
  size_t oWgupT = alloc((size_t)512*1024*4);        // 2 MB f32
  size_t oWuph  = alloc((size_t)512*32*152*2);      // 4.98 MB f16
  size_t oWqUqh = alloc((size_t)32*256*152*2);      // 2.49 MB f16
  size_t oWgcP  = alloc((size_t)512*1024*2);        // 1 MB f16
  size_t oWihP  = alloc((size_t)1024*450*2);        // 0.92 MB f16
  size_t oWhhU  = alloc((size_t)76*450*4);
  size_t oWvU   = alloc((size_t)76*152*4);
  size_t oX     = alloc((size_t)32*512*1024*2);     // Guph 33.5 MB (aliases WpT/WqT)
  size_t oWpT   = oX;                                // 0.3 MB f32, consumed before Guph written
  size_t oWqT   = oX + 310272;                       // 0.3 MB f32
  size_t need = off;
  if(ws_size < need) return;

  float* WgupT = (float*)(wsb + oWgupT);
  _Float16* Wuph  = (_Float16*)(wsb + oWuph);
  _Float16* WqUqh = (_Float16*)(wsb + oWqUqh);
  _Float16* WgcP  = (_Float16*)(wsb + oWgcP);
  _Float16* WihP  = (_Float16*)(wsb + oWihP);
  unsigned* WhhU  = (unsigned*)(wsb + oWhhU);
  unsigned* WvU   = (unsigned*)(wsb + oWvU);
  _Float16* Guph  = (_Float16*)(wsb + oX);
  float* WpT = (float*)(wsb + oWpT);
  float* WqT = (float*)(wsb + oWqT);

  // folds + precompute GEMMs (stream-ordered; Guph overwrites WpT/WqT after use)
  k_fold<<<256,256,0,stream>>>(Wp,Wq,Wg, WpT,WqT,WgupT);
  k_fold2<<<512,256,0,stream>>>(Wg, W_ih, W_hh, Wv, WgcP, WihP, WhhU, WvU);
  k_gemm<0><<<dim3(512,1),256,0,stream>>>(up, WpT, Wuph, 150);
  k_gemm<3><<<dim3(256,1),256,0,stream>>>(uq, WqT, WqUqh, 150);
  k_gemm<4><<<dim3(512,4),256,0,stream>>>(up, WgupT, Guph, 1024);

  // persistent per-batch scan: 32 independent blocks, no inter-block sync.
  // 100KB dynamic LDS forces 1 block/CU (no co-residency stragglers).
  hipFuncSetAttribute((const void*)persist, hipFuncAttributeMaxDynamicSharedMemorySize, 100352);
  persist<<<32, 1024, 100352, stream>>>(uq, v0, Vm, b_ih, b_hh,
      Wuph, WqUqh, (const uint4*)WgcP, (const uint4*)WihP, WhhU, WvU, Guph, dout);
}

// Round 4
// 25967.792 us; speedup vs baseline: 1.6397x; 1.6397x over previous
//
#include <hip/hip_runtime.h>
#include <hip/hip_bf16.h>

#define AGENT __HIP_MEMORY_SCOPE_AGENT

typedef _Float16 h2 __attribute__((ext_vector_type(2)));
union U32H2 { unsigned u; h2 h; };
__device__ __forceinline__ h2 uh(unsigned u){ U32H2 c; c.u=u; return c.h; }
__device__ __forceinline__ unsigned pk(float a, float b){
  U32H2 c; c.h = h2{(_Float16)a, (_Float16)b}; return c.u;
}
#define RCPF(x) __builtin_amdgcn_rcpf(x)

__device__ __forceinline__ float DOT2(unsigned a, unsigned b, float acc){
#if __has_builtin(__builtin_amdgcn_fdot2)
  return __builtin_amdgcn_fdot2(uh(a), uh(b), acc, false);
#else
  h2 x = uh(a), y = uh(b);
  acc = fmaf((float)x[0], (float)y[0], acc);
  return fmaf((float)x[1], (float)y[1], acc);
#endif
}
__device__ __forceinline__ float sigm(float x){ return RCPF(1.0f+__expf(-x)); }
__device__ __forceinline__ float ftanh(float x){ return 1.0f - 2.0f*RCPF(1.0f+__expf(x+x)); }
__device__ __forceinline__ float wredmax(float v){
  #pragma unroll
  for(int o=1;o<64;o<<=1) v = fmaxf(v, __shfl_xor(v,o,64));
  return v;
}
__device__ __forceinline__ float wredsum(float v){
  #pragma unroll
  for(int o=1;o<64;o<<=1) v += __shfl_xor(v,o,64);
  return v;
}

// ---------------- one-time weight folds (f32 GEMM inputs) ----------------
__global__ void k_fold(const float* __restrict__ Wp, const float* __restrict__ Wq,
                       const float* __restrict__ Wg,
                       float* __restrict__ WpT, float* __restrict__ WqT,
                       float* __restrict__ WgupT)
{
  int i0 = blockIdx.x*blockDim.x+threadIdx.x;
  int st = gridDim.x*blockDim.x;
  for(int o=i0;o<512*150;o+=st){ int h=o%150, i=o/150;
    WpT[o]=Wp[h*1024+i]+Wp[h*1024+512+i];
    WqT[o]=Wq[h*1024+i]+Wq[h*1024+512+i]; }
  for(int o=i0;o<512*1024;o+=st){ int i=o&511, j=o>>9;
    size_t rb=(size_t)(1024+j)*2048;
    WgupT[(size_t)i*1024+j]=Wg[rb+i]+Wg[rb+512+i]; }
}

// ---------------- f16-pair weight layouts for the persistent kernel ----------------
__global__ void k_fold2(const float* __restrict__ Wih,
                        const float* __restrict__ Whh, const float* __restrict__ Wv,
                        _Float16* __restrict__ WihP,
                        unsigned* __restrict__ WhhU, unsigned* __restrict__ WvU)
{
  int i0 = blockIdx.x*blockDim.x+threadIdx.x;
  int st = gridDim.x*blockDim.x;
  // WihP[((j/8)*450 + k)*8 + j%8]
  for(int o=i0;o<450*1024;o+=st){ int j=o&1023, k=o>>10;
    WihP[((size_t)(j>>3)*450 + k)*8 + (j&7)] = (_Float16)Wih[(size_t)k*1024 + j]; }
  // WhhU[p*450+k] = pair (Whh[k,2p], Whh[k,2p+1]), zero-padded
  for(int o=i0;o<76*450;o+=st){ int k=o%450, p=o/450;
    float x = (2*p<150)? Whh[k*150+2*p] : 0.f;
    float y = (2*p+1<150)? Whh[k*150+2*p+1] : 0.f;
    WhhU[p*450+k] = pk(x,y); }
  // WvU[p*152+h] = pair (Wv[h,2p], Wv[h,2p+1])
  for(int o=i0;o<76*150;o+=st){ int h=o%150, p=o/150;
    float x = (2*p<150)? Wv[h*150+2*p] : 0.f;
    float y = (2*p+1<150)? Wv[h*150+2*p+1] : 0.f;
    WvU[p*152+h] = pk(x,y); }
}

// uq (q,b,i) f32 -> uqh (b,q,i) f16 pair-words
__global__ void k_uqh(const float* __restrict__ uq, unsigned* __restrict__ uqh32){
  int idx = blockIdx.x*blockDim.x + threadIdx.x;   // word index
  if(idx >= 32*256*256) return;
  int iw = idx & 255; int rest = idx >> 8;
  int q = rest & 255; int b = rest >> 8;
  const float* src = uq + ((size_t)q*32 + b)*512 + iw*2;
  uqh32[idx] = pk(src[0], src[1]);
}

// ---------------- precompute GEMMs, f16 outputs ----------------
// MODE 0: Wuph[(t*32+b)*150+h]  N=150
// MODE 3: WqUqh[(b*256+q)*152+h] N=150 (pad 152 for u32 view)
// MODE 4: Guph[(b*512+t)*1024+j] N=1024
template<int MODE>
__global__ __launch_bounds__(256) void k_gemm(const float* __restrict__ A,
   const float* __restrict__ WT, _Float16* __restrict__ oH, int N)
{
  __shared__ float Al[32*512];
  int mt=blockIdx.x, nt=blockIdx.y, tid=threadIdx.x;
  const float* Ab = A + (size_t)mt*16384;
  for(int o=tid;o<4096;o+=256) ((float4*)Al)[o]=((const float4*)Ab)[o];
  __syncthreads();
  int n = nt*256+tid;
  if(n>=N) return;
  float acc[32];
  #pragma unroll
  for(int m=0;m<32;m++) acc[m]=0.f;
  const float* wp = WT + n;
  #pragma unroll 2
  for(int k=0;k<512;k+=2){
    float w0 = wp[(size_t)k*N], w1 = wp[(size_t)(k+1)*N];
    #pragma unroll
    for(int m=0;m<32;m++) acc[m]=fmaf(w0, Al[m*512+k], acc[m]);
    #pragma unroll
    for(int m=0;m<32;m++) acc[m]=fmaf(w1, Al[m*512+k+1], acc[m]);
  }
  if(MODE==0){
    #pragma unroll
    for(int m=0;m<32;m++) oH[((size_t)mt*32+m)*150 + n] = (_Float16)acc[m];
  } else if(MODE==3){
    #pragma unroll
    for(int m=0;m<32;m++) oH[((size_t)m*256+mt)*152 + n] = (_Float16)acc[m];
  } else {
    #pragma unroll
    for(int m=0;m<32;m++) oH[((size_t)m*512+mt)*1024 + n] = (_Float16)acc[m];
  }
}

__global__ void k_init(unsigned* flags){
  int i = blockIdx.x*blockDim.x + threadIdx.x;
  if(i < 32*4*8*16) flags[i] = 0u;
}

// ---------------- persistent kernel: 32 groups x 8 blocks, flag sync ----------------
struct __align__(16) SM {
  unsigned Wgc[128*257];     // j-slice (128 j) x 256 pairwords, pad 257
  unsigned WqUq[32*76];      // q-slice f16 pairs
  unsigned vp[80];
  float v_[152];
  float V_[152];
  float w2[152];
  float s_[256];
  float a_[256];
  float ccf[512];
  unsigned ccp[256];
  float bi[3][20];
  float bh[3][20];
  union {
    float2 red[16][33];
    struct { unsigned cp[512]; float gi[3][20]; float gh[3][20]; } p4;
  } u;
};

__device__ __forceinline__ void poll_ge(const unsigned* f, unsigned target){
  long n=0;
  while(__hip_atomic_load(f, __ATOMIC_ACQUIRE, AGENT) < target){
    __builtin_amdgcn_s_sleep(1);
    if(++n > 20000000L) break;   // bail instead of hanging
  }
}

__global__ __launch_bounds__(1024) void persist(
  const unsigned* __restrict__ uqh32, const float* __restrict__ v0,
  const float* __restrict__ Vin, const float* __restrict__ Wg,
  const float* __restrict__ bih, const float* __restrict__ bhh,
  const _Float16* __restrict__ Wuph, const _Float16* __restrict__ WqUqh,
  const uint4* __restrict__ WihP4, const unsigned* __restrict__ WhhU,
  const unsigned* __restrict__ WvU, const _Float16* __restrict__ Guph,
  float* sbuf, float* ccbuf, unsigned* cpbuf, float* vbuf, unsigned* flags,
  float* __restrict__ dout)
{
  extern __shared__ char smraw[];
  SM& S = *reinterpret_cast<SM*>(smraw);
  const int tid = threadIdx.x;
  const int r = blockIdx.x >> 5;          // slice id 0..7
  const int b = blockIdx.x & 31;          // batch (group); group b on XCD b%8
  const int hs = (r*150)>>3, he = ((r+1)*150)>>3, nh = he-hs;
  unsigned* flg = flags + (size_t)b*4*8*16;  // [phase][r][16]

  // ================= prologue: pin LDS =================
  for(int o=tid;o<128*256;o+=1024){
    int j8=o>>8, w=o&255;
    size_t rb = (size_t)(1024 + r*128 + j8)*2048;
    float x0 = Wg[rb+1024+2*w]   + Wg[rb+1536+2*w];
    float x1 = Wg[rb+1024+2*w+1] + Wg[rb+1536+2*w+1];
    S.Wgc[j8*257+w] = pk(x0,x1);
  }
  const unsigned* wquq_u = (const unsigned*)WqUqh;
  for(int o=tid;o<32*76;o+=1024){
    int q=o/76, w=o%76;
    S.WqUq[q*76+w] = wquq_u[((size_t)b*256 + r*32 + q)*76 + w];
  }
  for(int o=tid;o<152;o+=1024){
    S.V_[o] = (o<150)? Vin[b*150+o] : 0.f;
    S.v_[o] = (o<150)? v0[b*150+o] : 0.f;
  }
  for(int o=tid;o<60;o+=1024){
    int g=o/20, hi=o%20;
    bool ok = (hi<nh);
    S.bi[g][hi] = ok? bih[g*150+hs+hi] : 0.f;
    S.bh[g][hi] = ok? bhh[g*150+hs+hi] : 0.f;
  }
  __syncthreads();
  if(tid<80) S.vp[tid] = (tid<76)? pk(S.v_[2*tid], S.v_[2*tid+1]) : 0u;
  __syncthreads();

  // ================= 512-step scan =================
  for(int t=0; t<512; ++t){
    // ---- phase 1: reload v (t>0), w2 = Wup + Wv.v, s[Qr] ----
    if(t>0){
      if(tid<8) poll_ge(&flg[(3*8+tid)*16], (unsigned)t);
      __syncthreads();
      if(tid<152) S.v_[tid] = (tid<150)? __hip_atomic_load(&vbuf[b*152+tid], __ATOMIC_RELAXED, AGENT) : 0.f;
      __syncthreads();
      if(tid<76) S.vp[tid] = pk(S.v_[2*tid], S.v_[2*tid+1]);
      __syncthreads();
    }
    if(tid<608){
      int h=tid>>2, qd=tid&3;
      float acc=0.f;
      if(h<150){
        #pragma unroll
        for(int p=qd*19;p<qd*19+19;p++) acc = DOT2(WvU[p*152+h], S.vp[p], acc);
      }
      acc += __shfl_xor(acc,1,64); acc += __shfl_xor(acc,2,64);
      if(h<150 && qd==0) S.w2[h] = acc + (float)Wuph[((size_t)t*32+b)*150 + h];
    }
    __syncthreads();
    {
      int q = tid>>5, s32 = tid&31;
      int h0 = (s32*150)>>5, h1 = ((s32+1)*150)>>5;
      float acc=0.f;
      for(int h=h0;h<h1;h++){
        h2 wp = uh(S.WqUq[q*76 + (h>>1)]);
        float wv = (float)wp[h&1];
        acc = fmaf(S.V_[h], ftanh(S.w2[h] + wv), acc);
      }
      #pragma unroll
      for(int o=1;o<32;o<<=1) acc += __shfl_xor(acc,o,64);
      if(s32==0) __hip_atomic_store(&sbuf[b*256 + r*32 + q], acc, __ATOMIC_RELAXED, AGENT);
    }
    __syncthreads();
    if(tid==0) __hip_atomic_store(&flg[(0*8+r)*16], (unsigned)(t+1), __ATOMIC_RELEASE, AGENT);

    // ---- phase 2: softmax (redundant) + cc[Ir] ----
    if(tid<8) poll_ge(&flg[(0*8+tid)*16], (unsigned)(t+1));
    __syncthreads();
    if(tid<256) S.s_[tid] = __hip_atomic_load(&sbuf[b*256+tid], __ATOMIC_RELAXED, AGENT);
    __syncthreads();
    if(tid<64){
      float x0=S.s_[tid],x1=S.s_[tid+64],x2=S.s_[tid+128],x3=S.s_[tid+192];
      float mx = wredmax(fmaxf(fmaxf(x0,x1),fmaxf(x2,x3)));
      float e0=__expf(x0-mx),e1=__expf(x1-mx),e2=__expf(x2-mx),e3=__expf(x3-mx);
      float rs = RCPF(wredsum(e0+e1+e2+e3));
      S.a_[tid]=e0*rs; S.a_[tid+64]=e1*rs; S.a_[tid+128]=e2*rs; S.a_[tid+192]=e3*rs;
    }
    __syncthreads();
    {
      int iw = tid&31, qc = tid>>5;          // 32 q-chunks of 8
      float a0=0.f, a1=0.f;
      const unsigned* up = uqh32 + ((size_t)b*256 + qc*8)*256 + r*32 + iw;
      #pragma unroll
      for(int qq=0;qq<8;qq++){
        float av = S.a_[qc*8+qq];
        h2 uv = uh(up[(size_t)qq*256]);
        a0 = fmaf(av,(float)uv[0],a0);
        a1 = fmaf(av,(float)uv[1],a1);
      }
      a0 += __shfl_xor(a0,32,64); a1 += __shfl_xor(a1,32,64);
      if((tid&32)==0) S.u.red[tid>>6][iw] = make_float2(a0,a1);
    }
    __syncthreads();
    if(tid<32){
      float c0=0.f,c1=0.f;
      #pragma unroll
      for(int k2=0;k2<16;k2++){ float2 v2 = S.u.red[k2][tid]; c0+=v2.x; c1+=v2.y; }
      __hip_atomic_store(&ccbuf[b*512 + r*64 + 2*tid],   c0, __ATOMIC_RELAXED, AGENT);
      __hip_atomic_store(&ccbuf[b*512 + r*64 + 2*tid+1], c1, __ATOMIC_RELAXED, AGENT);
    }
    __syncthreads();
    if(tid==0) __hip_atomic_store(&flg[(1*8+r)*16], (unsigned)(t+1), __ATOMIC_RELEASE, AGENT);

    // ---- phase 3: Gc[Jr] from LDS Wgc, gate, c_[Jr] ----
    if(tid<8) poll_ge(&flg[(1*8+tid)*16], (unsigned)(t+1));
    __syncthreads();
    if(tid<512) S.ccf[tid] = __hip_atomic_load(&ccbuf[b*512+tid], __ATOMIC_RELAXED, AGENT);
    __syncthreads();
    if(tid<256) S.ccp[tid] = pk(S.ccf[2*tid], S.ccf[2*tid+1]);
    __syncthreads();
    {
      int j8 = tid>>3, s8 = tid&7;
      float acc=0.f;
      #pragma unroll 4
      for(int i=0;i<32;i++){
        int p = s8*4 + (i&3) + (i&~3)*8;   // coset walk: bank-conflict-free
        acc = DOT2(S.Wgc[j8*257+p], S.ccp[p], acc);
      }
      acc += __shfl_xor(acc,1,64); acc += __shfl_xor(acc,2,64); acc += __shfl_xor(acc,4,64);
      float val=0.f;
      int j = r*128 + j8;
      if(s8==0){
        float g = sigm(acc + (float)Guph[((size_t)b*512+t)*1024 + j]);
        val = g * S.ccf[j&511];
      }
      float o2 = __shfl_xor(val,8,64);     // partner j8+1
      if(s8==0 && !(j8&1))
        __hip_atomic_store(&cpbuf[b*512 + (j>>1)], pk(val,o2), __ATOMIC_RELAXED, AGENT);
    }
    __syncthreads();
    if(tid==0) __hip_atomic_store(&flg[(2*8+r)*16], (unsigned)(t+1), __ATOMIC_RELEASE, AGENT);

    // ---- phase 4: gi[Kr], gh[Kr], GRU, v[Hr] ----
    if(tid<8) poll_ge(&flg[(2*8+tid)*16], (unsigned)(t+1));
    __syncthreads();
    if(tid<512){
      unsigned w = (unsigned)tid;
      S.u.p4.cp[w ^ ((((w>>5)&7))<<2)] = __hip_atomic_load(&cpbuf[b*512+tid], __ATOMIC_RELAXED, AGENT);
    }
    __syncthreads();
    {
      int slot = tid>>4, s16 = tid&15;
      int gate = slot/19, hi = slot%19;
      bool valid = (gate<3) && (hi<nh);
      float acc=0.f, ah=0.f;
      int k = gate*150 + hs + hi;
      if(valid){
        #pragma unroll
        for(int c8p=0;c8p<8;c8p++){
          int c8 = s16*8 + c8p;
          uint4 wv = WihP4[(size_t)c8*450 + k];
          int wb = c8*4; wb ^= ((wb>>5)&7)<<2;
          uint4 cp4 = *reinterpret_cast<const uint4*>(&S.u.p4.cp[wb]);
          acc = DOT2(wv.x,cp4.x,acc); acc = DOT2(wv.y,cp4.y,acc);
          acc = DOT2(wv.z,cp4.z,acc); acc = DOT2(wv.w,cp4.w,acc);
        }
        int p0 = s16*5, p1 = (p0+5>76)?76:(p0+5);
        for(int p=p0;p<p1;p++) ah = DOT2(WhhU[(size_t)p*450 + k], S.vp[p], ah);
      }
      #pragma unroll
      for(int o=1;o<16;o<<=1){ acc += __shfl_xor(acc,o,64); ah += __shfl_xor(ah,o,64); }
      if(valid && s16==0){ S.u.p4.gi[gate][hi]=acc; S.u.p4.gh[gate][hi]=ah; }
    }
    __syncthreads();
    if(tid<nh){
      int hi=tid, h=hs+hi;
      float gir=S.u.p4.gi[0][hi]+S.bi[0][hi], ghr=S.u.p4.gh[0][hi]+S.bh[0][hi];
      float giz=S.u.p4.gi[1][hi]+S.bi[1][hi], ghz=S.u.p4.gh[1][hi]+S.bh[1][hi];
      float gin=S.u.p4.gi[2][hi]+S.bi[2][hi], ghn=S.u.p4.gh[2][hi]+S.bh[2][hi];
      float rg = sigm(gir+ghr), zg = sigm(giz+ghz);
      float ng = ftanh(gin + rg*ghn);
      float vn = fmaf(zg, S.v_[h]-ng, ng);
      __hip_atomic_store(&vbuf[b*152+h], vn, __ATOMIC_RELAXED, AGENT);
      dout[((size_t)t*32+b)*150 + h] = vn;
    }
    __syncthreads();
    if(tid==0) __hip_atomic_store(&flg[(3*8+r)*16], (unsigned)(t+1), __ATOMIC_RELEASE, AGENT);
  }
}

// ---------------- host ----------------
extern "C" void kernel_launch(void* const* d_in, const int* in_sizes, int n_in,
                              void* d_out, int out_size, void* d_ws, size_t ws_size,
                              hipStream_t stream)
{
  const float* up  = (const float*)d_in[0];
  const float* uq  = (const float*)d_in[1];
  const float* v0  = (const float*)d_in[2];
  const float* Vm  = (const float*)d_in[3];
  const float* Wp  = (const float*)d_in[4];
  const float* Wq  = (const float*)d_in[5];
  const float* Wv  = (const float*)d_in[6];
  const float* Wg  = (const float*)d_in[7];
  const float* W_ih= (const float*)d_in[8];
  const float* W_hh= (const float*)d_in[9];
  const float* b_ih= (const float*)d_in[10];
  const float* b_hh= (const float*)d_in[11];
  float* dout = (float*)d_out;
  char* wsb = (char*)d_ws;

  size_t off = 0;
  auto alloc = [&](size_t bytes)->size_t{ size_t p = off; off = (off + bytes + 255) & ~(size_t)255; return p; };
  size_t oWgupT = alloc((size_t)512*1024*4);      // 2MB; persist-time bufs alias inside
  size_t oWuph  = alloc((size_t)512*32*150*2);
  size_t oWqUqh = alloc((size_t)32*256*152*2);
  size_t oWihP  = alloc((size_t)450*1024*2);
  size_t oWhhU  = alloc((size_t)76*450*4);
  size_t oWvU   = alloc((size_t)76*152*4);
  size_t oUqh   = alloc((size_t)32*256*512*2);
  size_t oGuph  = alloc((size_t)32*512*1024*2);   // WpT/WqT alias at start (dead before write)
  if(ws_size < off) return;

  float*    WgupT = (float*)(wsb + oWgupT);
  _Float16* Wuph  = (_Float16*)(wsb + oWuph);
  _Float16* WqUqh = (_Float16*)(wsb + oWqUqh);
  _Float16* WihP  = (_Float16*)(wsb + oWihP);
  unsigned* WhhU  = (unsigned*)(wsb + oWhhU);
  unsigned* WvU   = (unsigned*)(wsb + oWvU);
  unsigned* uqh32 = (unsigned*)(wsb + oUqh);
  _Float16* Guph  = (_Float16*)(wsb + oGuph);
  float* WpT = (float*)(wsb + oGuph);                     // 307200B, dead before Guph written
  float* WqT = (float*)(wsb + oGuph + 307456);

  // persist-time small buffers alias the (then-dead) WgupT region
  float*    sbuf  = (float*)(wsb + oWgupT);               // 32KB
  float*    ccbuf = (float*)(wsb + oWgupT + 32768);       // 64KB
  unsigned* cpbuf = (unsigned*)(wsb + oWgupT + 98304);    // 64KB
  float*    vbuf  = (float*)(wsb + oWgupT + 163840);      // 19KB
  unsigned* flags = (unsigned*)(wsb + oWgupT + 185344);   // 64KB

  k_fold <<<256,256,0,stream>>>(Wp,Wq,Wg, WpT,WqT,WgupT);
  k_fold2<<<512,256,0,stream>>>(W_ih, W_hh, Wv, WihP, WhhU, WvU);
  k_uqh  <<<2048,1024,0,stream>>>(uq, uqh32);
  k_gemm<0><<<dim3(512,1),256,0,stream>>>(up, WpT, Wuph, 150);
  k_gemm<3><<<dim3(256,1),256,0,stream>>>(uq, WqT, WqUqh, 150);
  k_gemm<4><<<dim3(512,4),256,0,stream>>>(up, WgupT, Guph, 1024);   // WpT/WqT dead now
  k_init <<<16,1024,0,stream>>>(flags);                              // WgupT dead now

  hipFuncSetAttribute((const void*)persist, hipFuncAttributeMaxDynamicSharedMemorySize, (int)sizeof(SM));
  void* ka[18] = { (void*)&uqh32, (void*)&v0, (void*)&Vm, (void*)&Wg,
                   (void*)&b_ih, (void*)&b_hh, (void*)&Wuph, (void*)&WqUqh,
                   (void*)&WihP, (void*)&WhhU, (void*)&WvU, (void*)&Guph,
                   (void*)&sbuf, (void*)&ccbuf, (void*)&cpbuf, (void*)&vbuf,
                   (void*)&flags, (void*)&dout };
  hipLaunchCooperativeKernel((const void*)persist, dim3(256), dim3(1024), ka,
                             (unsigned)sizeof(SM), stream);
}

// Round 5
// 15307.994 us; speedup vs baseline: 2.7815x; 1.6964x over previous
//
#include <hip/hip_runtime.h>
#include <hip/hip_bf16.h>

#define AGENT __HIP_MEMORY_SCOPE_AGENT
#define RLX __ATOMIC_RELAXED

typedef _Float16 h2 __attribute__((ext_vector_type(2)));
union U32H2 { unsigned u; h2 h; };
__device__ __forceinline__ h2 uh(unsigned u){ U32H2 c; c.u=u; return c.h; }
__device__ __forceinline__ unsigned pk(float a, float b){
  U32H2 c; c.h = h2{(_Float16)a, (_Float16)b}; return c.u;
}
#define RCPF(x) __builtin_amdgcn_rcpf(x)
// per-wave drain of outstanding global stores (before flag publish)
#define DRAIN() asm volatile("s_waitcnt vmcnt(0)" ::: "memory")

__device__ __forceinline__ float DOT2(unsigned a, unsigned b, float acc){
#if __has_builtin(__builtin_amdgcn_fdot2)
  return __builtin_amdgcn_fdot2(uh(a), uh(b), acc, false);
#else
  h2 x = uh(a), y = uh(b);
  acc = fmaf((float)x[0], (float)y[0], acc);
  return fmaf((float)x[1], (float)y[1], acc);
#endif
}
__device__ __forceinline__ float sigm(float x){ return RCPF(1.0f+__expf(-x)); }
__device__ __forceinline__ float ftanh(float x){ return 1.0f - 2.0f*RCPF(1.0f+__expf(x+x)); }
__device__ __forceinline__ float wredmax(float v){
  #pragma unroll
  for(int o=1;o<64;o<<=1) v = fmaxf(v, __shfl_xor(v,o,64));
  return v;
}
__device__ __forceinline__ float wredsum(float v){
  #pragma unroll
  for(int o=1;o<64;o<<=1) v += __shfl_xor(v,o,64);
  return v;
}
// relaxed spin (NO acquire -> no L2 invalidates)
__device__ __forceinline__ void poll_ge(const unsigned* f, unsigned tgt){
  long n=0;
  while(__hip_atomic_load(f, RLX, AGENT) < tgt){
    __builtin_amdgcn_s_sleep(1);
    if(++n > 20000000L) break;
  }
}

// ---------------- one-time weight folds (f32 GEMM inputs) ----------------
__global__ void k_fold(const float* __restrict__ Wp, const float* __restrict__ Wq,
                       const float* __restrict__ Wg,
                       float* __restrict__ WpT, float* __restrict__ WqT,
                       float* __restrict__ WgupT, float* __restrict__ WgcT)
{
  int i0 = blockIdx.x*blockDim.x+threadIdx.x;
  int st = gridDim.x*blockDim.x;
  for(int o=i0;o<512*150;o+=st){ int h=o%150, i=o/150;
    WpT[o]=Wp[h*1024+i]+Wp[h*1024+512+i];
    WqT[o]=Wq[h*1024+i]+Wq[h*1024+512+i]; }
  for(int o=i0;o<512*1024;o+=st){ int i=o&511, j=o>>9;
    size_t rb=(size_t)(1024+j)*2048;
    WgupT[(size_t)i*1024+j]=Wg[rb+i]+Wg[rb+512+i];
    WgcT [(size_t)i*1024+j]=Wg[rb+1024+i]+Wg[rb+1536+i]; }
}

// f16-pair layouts: WihP[k*512+jp], WhhP[p*456+k], WvU[p*152+h]
__global__ void k_fold2(const float* __restrict__ Wih,
                        const float* __restrict__ Whh, const float* __restrict__ Wv,
                        unsigned* __restrict__ WihP,
                        unsigned* __restrict__ WhhP, unsigned* __restrict__ WvU)
{
  int i0 = blockIdx.x*blockDim.x+threadIdx.x;
  int st = gridDim.x*blockDim.x;
  for(int o=i0;o<450*512;o+=st){ int jp=o&511, k=o>>9;
    WihP[o] = pk(Wih[(size_t)k*1024+2*jp], Wih[(size_t)k*1024+2*jp+1]); }
  for(int o=i0;o<76*456;o+=st){ int k=o%456, p=o/456;
    float x=0.f,y=0.f;
    if(k<450){ if(2*p<150) x=Whh[k*150+2*p]; if(2*p+1<150) y=Whh[k*150+2*p+1]; }
    WhhP[o]=pk(x,y); }
  for(int o=i0;o<76*152;o+=st){ int h=o%152, p=o/152;
    float x=0.f,y=0.f;
    if(h<150){ if(2*p<150) x=Wv[h*150+2*p]; if(2*p+1<150) y=Wv[h*150+2*p+1]; }
    WvU[o]=pk(x,y); }
}

// uq (q,b,i) f32 -> uqP[(b*512+i)*128 + qp] = pk over q-pairs
__global__ __launch_bounds__(256) void k_uqp(const float* __restrict__ uq, unsigned* __restrict__ uqP){
  __shared__ float Al[32*512];
  int b = blockIdx.x, qt = blockIdx.y, tid = threadIdx.x;
  for(int o4=tid;o4<4096;o4+=256){ int m=o4>>7, i4=o4&127;
    ((float4*)Al)[o4] = *(const float4*)&uq[(size_t)(qt*32+m)*16384 + b*512 + i4*4]; }
  __syncthreads();
  for(int o=tid;o<8192;o+=256){ int i=o>>4, p=o&15;
    uqP[((size_t)b*512+i)*128 + qt*16 + p] = pk(Al[(2*p)*512+i], Al[(2*p+1)*512+i]); }
}

// precompute GEMMs (A-tile 32 rows of 512; validated structure)
// MODE 0: Wuph[b][t][152]   MODE 3: WqUqh[b][q][152]   MODE 4: Gup2[t][j][32b]
template<int MODE>
__global__ __launch_bounds__(256) void k_gemm(const float* __restrict__ A,
   const float* __restrict__ WT, _Float16* __restrict__ oH, int N)
{
  __shared__ float Al[32*512];
  int mt=blockIdx.x, nt=blockIdx.y, tid=threadIdx.x;
  const float* Ab = A + (size_t)mt*16384;
  for(int o=tid;o<4096;o+=256) ((float4*)Al)[o]=((const float4*)Ab)[o];
  __syncthreads();
  int n = nt*256+tid;
  if(n>=N) return;
  float acc[32];
  #pragma unroll
  for(int m=0;m<32;m++) acc[m]=0.f;
  const float* wp = WT + n;
  #pragma unroll 2
  for(int k=0;k<512;k+=2){
    float w0 = wp[(size_t)k*N], w1 = wp[(size_t)(k+1)*N];
    #pragma unroll
    for(int m=0;m<32;m++) acc[m]=fmaf(w0, Al[m*512+k], acc[m]);
    #pragma unroll
    for(int m=0;m<32;m++) acc[m]=fmaf(w1, Al[m*512+k+1], acc[m]);
  }
  if(MODE==0){
    #pragma unroll
    for(int m=0;m<32;m++) oH[((size_t)m*512 + mt)*152 + n] = (_Float16)acc[m];
  } else if(MODE==3){
    #pragma unroll
    for(int m=0;m<32;m++) oH[((size_t)m*256 + mt)*152 + n] = (_Float16)acc[m];
  } else {
    #pragma unroll
    for(int m=0;m<32;m++) oH[(((size_t)mt*1024) + n)*32 + m] = (_Float16)acc[m];
  }
}

// M[b] = uq[b] @ WgcT : Mp[(b*1024+j)*128 + qp] = pk(M[2qp,j], M[2qp+1,j])
__global__ __launch_bounds__(256) void k_gemmM(const float* __restrict__ uq,
   const float* __restrict__ WgcT, unsigned* __restrict__ Mp)
{
  __shared__ float Al[32*512];
  int b=blockIdx.x, qt=blockIdx.y, nt=blockIdx.z, tid=threadIdx.x;
  for(int o4=tid;o4<4096;o4+=256){ int m=o4>>7, i4=o4&127;
    ((float4*)Al)[o4] = *(const float4*)&uq[(size_t)(qt*32+m)*16384 + b*512 + i4*4]; }
  __syncthreads();
  int n = nt*256+tid;
  float acc[32];
  #pragma unroll
  for(int m=0;m<32;m++) acc[m]=0.f;
  const float* wp = WgcT + n;
  #pragma unroll 2
  for(int k=0;k<512;k+=2){
    float w0 = wp[(size_t)k*1024], w1 = wp[(size_t)(k+1)*1024];
    #pragma unroll
    for(int m=0;m<32;m++) acc[m]=fmaf(w0, Al[m*512+k], acc[m]);
    #pragma unroll
    for(int m=0;m<32;m++) acc[m]=fmaf(w1, Al[m*512+k+1], acc[m]);
  }
  #pragma unroll
  for(int p=0;p<16;p++)
    Mp[((size_t)b*1024 + n)*128 + qt*16 + p] = pk(acc[2*p], acc[2*p+1]);
}

__global__ void k_init(unsigned* flags){
  int i = blockIdx.x*blockDim.x + threadIdx.x;
  if(i < 4096) flags[i] = 0u;
}

// ---------------- persistent: 254 blocks, weight-stationary roles ----------------
struct __align__(16) SM {
  union U {
    struct { unsigned WqUq[256*76]; unsigned WvU[76*152]; unsigned wup[80]; unsigned vp[80];
             float V[152]; float v[152]; float w2[152]; float s[256]; float a[256];
             float gi[452]; float gh[452]; float bi[452]; float bh[452]; } o;
    struct { unsigned uq[32768]; unsigned al[4096]; float red[8][32][4]; } c;
    struct { unsigned Mp[32768]; unsigned al[4096]; float red[8][32][4];
             float gtmp[8][32]; unsigned gup[128]; } g;
    struct { unsigned cw[16384]; unsigned Wih[16*512]; unsigned Whh[76*16];
             unsigned vl[2432]; float rgi[16][32][2]; float rgh[16][32][2]; } i;
  } u;
};

__global__ __launch_bounds__(1024) void persist(
  const unsigned* __restrict__ uqP, const unsigned* __restrict__ Mp,
  const _Float16* __restrict__ Gup2, const _Float16* __restrict__ Wuph,
  const _Float16* __restrict__ WqUqh, const unsigned* __restrict__ WihP,
  const unsigned* __restrict__ WhhP, const unsigned* __restrict__ WvU,
  const float* __restrict__ v0, const float* __restrict__ Vin,
  const float* __restrict__ bih, const float* __restrict__ bhh,
  unsigned* a_pub, unsigned* v_pub, unsigned* cc_pub, unsigned* g_pub,
  float* gi_pub, float* gh_pub, unsigned* flags,
  float* __restrict__ dout)
{
  extern __shared__ char smraw[];
  SM& S = *reinterpret_cast<SM*>(smraw);
  const int tid = threadIdx.x;
  const int bid = blockIdx.x;

  if(bid < 32){
    // ================= OWNER (one per batch b) =================
    const int b = bid;
    const unsigned* wqg = (const unsigned*)WqUqh;
    for(int o=tid;o<19456;o+=1024){ int q=o/76, w=o%76;
      S.u.o.WqUq[o] = wqg[((size_t)b*256+q)*76 + w]; }
    for(int o=tid;o<11552;o+=1024) S.u.o.WvU[o] = WvU[o];
    for(int o=tid;o<152;o+=1024) S.u.o.V[o] = (o<150)? Vin[b*150+o] : 0.f;
    for(int o=tid;o<452;o+=1024){
      S.u.o.bi[o] = (o<450)? bih[o] : 0.f;
      S.u.o.bh[o] = (o<450)? bhh[o] : 0.f; }
    __syncthreads();

    for(int t=0;t<512;++t){
      if(tid<76) S.u.o.wup[tid] = ((const unsigned*)Wuph)[(size_t)(b*512+t)*76 + tid];
      if(t>0){
        if(tid<30) poll_ge(flags + (224+tid)*16, (unsigned)t);
        __syncthreads();
        if(tid<450){
          S.u.o.gi[tid] = __hip_atomic_load(gi_pub + tid*32 + b, RLX, AGENT);
          S.u.o.gh[tid] = __hip_atomic_load(gh_pub + tid*32 + b, RLX, AGENT); }
        __syncthreads();
        if(tid<150){
          float gir=S.u.o.gi[tid]+S.u.o.bi[tid],         ghr=S.u.o.gh[tid]+S.u.o.bh[tid];
          float giz=S.u.o.gi[150+tid]+S.u.o.bi[150+tid], ghz=S.u.o.gh[150+tid]+S.u.o.bh[150+tid];
          float gin=S.u.o.gi[300+tid]+S.u.o.bi[300+tid], ghn=S.u.o.gh[300+tid]+S.u.o.bh[300+tid];
          float rg=sigm(gir+ghr), zg=sigm(giz+ghz);
          float ng=ftanh(gin + rg*ghn);
          float vn=fmaf(zg, S.u.o.v[tid]-ng, ng);
          S.u.o.v[tid]=vn;
          dout[((size_t)(t-1)*32+b)*150+tid]=vn; }
        __syncthreads();
      } else {
        if(tid<152) S.u.o.v[tid] = (tid<150)? v0[b*150+tid] : 0.f;
        __syncthreads();
      }
      if(tid<76){
        unsigned w = pk(S.u.o.v[2*tid], S.u.o.v[2*tid+1]);
        S.u.o.vp[tid]=w;
        __hip_atomic_store(v_pub + tid*32 + b, w, RLX, AGENT); }
      __syncthreads();
      // w2 = Wup[t] + Wv.v
      if(tid<608){
        int h=tid>>2, qd=tid&3;
        float acc=0.f;
        if(h<150){
          #pragma unroll
          for(int p=qd*19;p<qd*19+19;p++) acc = DOT2(S.u.o.WvU[p*152+h], S.u.o.vp[p], acc);
        }
        acc += __shfl_xor(acc,1,64); acc += __shfl_xor(acc,2,64);
        if(h<150 && qd==0){
          h2 ww = uh(S.u.o.wup[h>>1]);
          S.u.o.w2[h] = acc + (float)ww[h&1]; }
      }
      __syncthreads();
      // s[q] = sum_h V[h] tanh(w2[h]+WqUq[q,h])
      {
        int q=tid>>2, hq=tid&3;
        int hp0=hq*19, hp1 = (hq==3)? 75 : hp0+19;
        float acc=0.f;
        for(int hp=hp0;hp<hp1;hp++){
          h2 wp = uh(S.u.o.WqUq[q*76+hp]);
          acc = fmaf(S.u.o.V[2*hp],   ftanh(S.u.o.w2[2*hp]   + (float)wp[0]), acc);
          acc = fmaf(S.u.o.V[2*hp+1], ftanh(S.u.o.w2[2*hp+1] + (float)wp[1]), acc);
        }
        acc += __shfl_xor(acc,1,64); acc += __shfl_xor(acc,2,64);
        if(hq==0) S.u.o.s[q]=acc;
      }
      __syncthreads();
      if(tid<64){
        float x0=S.u.o.s[tid],x1=S.u.o.s[tid+64],x2=S.u.o.s[tid+128],x3=S.u.o.s[tid+192];
        float mx = wredmax(fmaxf(fmaxf(x0,x1),fmaxf(x2,x3)));
        float e0=__expf(x0-mx),e1=__expf(x1-mx),e2=__expf(x2-mx),e3=__expf(x3-mx);
        float rs = RCPF(wredsum(e0+e1+e2+e3));
        S.u.o.a[tid]=e0*rs; S.u.o.a[tid+64]=e1*rs; S.u.o.a[tid+128]=e2*rs; S.u.o.a[tid+192]=e3*rs;
      }
      __syncthreads();
      if(tid<128)
        __hip_atomic_store(a_pub + tid*32 + b, pk(S.u.o.a[2*tid], S.u.o.a[2*tid+1]), RLX, AGENT);
      DRAIN();
      __syncthreads();
      if(tid==0) __hip_atomic_store(flags + b*16, (unsigned)(t+1), RLX, AGENT);
    }
    // epilogue: v_512 -> dout[511]
    if(tid<30) poll_ge(flags + (224+tid)*16, 512u);
    __syncthreads();
    if(tid<450){
      S.u.o.gi[tid] = __hip_atomic_load(gi_pub + tid*32 + b, RLX, AGENT);
      S.u.o.gh[tid] = __hip_atomic_load(gh_pub + tid*32 + b, RLX, AGENT); }
    __syncthreads();
    if(tid<150){
      float gir=S.u.o.gi[tid]+S.u.o.bi[tid],         ghr=S.u.o.gh[tid]+S.u.o.bh[tid];
      float giz=S.u.o.gi[150+tid]+S.u.o.bi[150+tid], ghz=S.u.o.gh[150+tid]+S.u.o.bh[150+tid];
      float gin=S.u.o.gi[300+tid]+S.u.o.bi[300+tid], ghn=S.u.o.gh[300+tid]+S.u.o.bh[300+tid];
      float rg=sigm(gir+ghr), zg=sigm(giz+ghz);
      float ng=ftanh(gin + rg*ghn);
      dout[((size_t)511*32+b)*150+tid] = fmaf(zg, S.u.o.v[tid]-ng, ng); }

  } else if(bid < 96){
    // ================= CC (i-slice of 8, all b) =================
    const int ic = bid-32;
    for(int o=tid;o<32768;o+=1024){
      int qp=o&127, il=(o>>7)&7, bb=o>>10;
      S.u.c.uq[qp*256 + il*32 + bb] = uqP[((size_t)bb*512 + ic*8+il)*128 + qp]; }
    __syncthreads();
    for(int t=0;t<512;++t){
      if(tid<32) poll_ge(flags + tid*16, (unsigned)(t+1));
      __syncthreads();
      for(int o=tid;o<4096;o+=1024) S.u.c.al[o] = __hip_atomic_load(a_pub + o, RLX, AGENT);
      __syncthreads();
      {
        int bb=tid&31, il=(tid>>5)&7, qc=tid>>8;
        float acc=0.f;
        #pragma unroll 8
        for(int k=0;k<32;k++){
          int qp=qc*32+k;
          acc = DOT2(S.u.c.al[qp*32+bb], S.u.c.uq[qp*256+il*32+bb], acc); }
        S.u.c.red[il][bb][qc]=acc;
      }
      __syncthreads();
      if(tid<128){
        int ip=tid>>5, bb=tid&31;
        float c0 = S.u.c.red[2*ip][bb][0]+S.u.c.red[2*ip][bb][1]+S.u.c.red[2*ip][bb][2]+S.u.c.red[2*ip][bb][3];
        float c1 = S.u.c.red[2*ip+1][bb][0]+S.u.c.red[2*ip+1][bb][1]+S.u.c.red[2*ip+1][bb][2]+S.u.c.red[2*ip+1][bb][3];
        __hip_atomic_store(cc_pub + (ic*4+ip)*32 + bb, pk(c0,c1), RLX, AGENT);
      }
      DRAIN();
      __syncthreads();
      if(tid==0) __hip_atomic_store(flags + (32+ic)*16, (unsigned)(t+1), RLX, AGENT);
    }

  } else if(bid < 224){
    // ================= G (j-slice of 8: Gc = a.M, gate) =================
    const int jg = bid-96;
    const int j0 = jg*8;
    for(int o=tid;o<32768;o+=1024){
      int qp=o&127, jl=(o>>7)&7, bb=o>>10;
      S.u.g.Mp[qp*256 + jl*32 + bb] = Mp[((size_t)bb*1024 + j0+jl)*128 + qp]; }
    __syncthreads();
    for(int t=0;t<512;++t){
      if(tid<32) poll_ge(flags + tid*16, (unsigned)(t+1));
      if(tid<128) S.u.g.gup[tid] = ((const unsigned*)Gup2)[((size_t)t*1024 + j0)*16 + tid];
      __syncthreads();
      for(int o=tid;o<4096;o+=1024) S.u.g.al[o] = __hip_atomic_load(a_pub + o, RLX, AGENT);
      __syncthreads();
      {
        int bb=tid&31, jl=(tid>>5)&7, qc=tid>>8;
        float acc=0.f;
        #pragma unroll 8
        for(int k=0;k<32;k++){
          int qp=qc*32+k;
          acc = DOT2(S.u.g.al[qp*32+bb], S.u.g.Mp[qp*256+jl*32+bb], acc); }
        S.u.g.red[jl][bb][qc]=acc;
      }
      __syncthreads();
      if(tid<256){
        int jl=tid>>5, bb=tid&31;
        float Gc = S.u.g.red[jl][bb][0]+S.u.g.red[jl][bb][1]+S.u.g.red[jl][bb][2]+S.u.g.red[jl][bb][3];
        int el = jl*32+bb;
        h2 gv = uh(S.u.g.gup[el>>1]);
        S.u.g.gtmp[jl][bb] = sigm(Gc + (float)gv[el&1]);
      }
      __syncthreads();
      if(tid<128){
        int jpl=tid>>5, bb=tid&31;
        __hip_atomic_store(g_pub + (jg*4+jpl)*32 + bb,
                           pk(S.u.g.gtmp[2*jpl][bb], S.u.g.gtmp[2*jpl+1][bb]), RLX, AGENT);
      }
      DRAIN();
      __syncthreads();
      if(tid==0) __hip_atomic_store(flags + (96+jg)*16, (unsigned)(t+1), RLX, AGENT);
    }

  } else if(bid < 254){
    // ================= I (k-slice of 15: gi = Wih.(g*cc), gh = Whh.v) =================
    const int ii = bid-224;
    const int k0 = ii*15;
    for(int o=tid;o<7680;o+=1024){ int kk=o>>9, jp=o&511;
      S.u.i.Wih[kk*512+jp] = WihP[(size_t)(k0+kk)*512 + jp]; }
    for(int o=tid;o<1216;o+=1024){ int p=o>>4, kk=o&15;
      S.u.i.Whh[p*16+kk] = (kk<15)? WhhP[p*456 + k0+kk] : 0u; }
    __syncthreads();
    for(int t=0;t<512;++t){
      if(tid<128) poll_ge(flags + (96+tid)*16, (unsigned)(t+1));
      else if(tid<192) poll_ge(flags + (32+(tid-128))*16, (unsigned)(t+1));
      __syncthreads();
      for(int o=tid;o<2432;o+=1024) S.u.i.vl[o] = __hip_atomic_load(v_pub + o, RLX, AGENT);
      for(int o=tid;o<16384;o+=1024){
        int jp=o>>5, bb=o&31;
        unsigned gw = __hip_atomic_load(g_pub + o, RLX, AGENT);
        unsigned cw = __hip_atomic_load(cc_pub + (jp&255)*32 + bb, RLX, AGENT);
        h2 g2=uh(gw), c2=uh(cw);
        S.u.i.cw[o] = pk((float)g2[0]*(float)c2[0], (float)g2[1]*(float)c2[1]);
      }
      __syncthreads();
      {
        int bb=tid&31, kk=(tid>>5)&15, hh=tid>>9;
        float acc=0.f, ah=0.f;
        if(kk<15){
          const unsigned* wr = &S.u.i.Wih[kk*512];
          #pragma unroll 8
          for(int jp=hh*256; jp<hh*256+256; jp++)
            acc = DOT2(wr[jp], S.u.i.cw[jp*32+bb], acc);
          int p1 = (hh==0)? 38 : 76;
          for(int p=hh*38; p<p1; p++)
            ah = DOT2(S.u.i.Whh[p*16+kk], S.u.i.vl[p*32+bb], ah);
        }
        S.u.i.rgi[kk][bb][hh]=acc;
        S.u.i.rgh[kk][bb][hh]=ah;
      }
      __syncthreads();
      if(tid<512){
        int kk=tid>>5, bb=tid&31;
        if(kk<15){
          __hip_atomic_store(gi_pub + (k0+kk)*32 + bb,
                             S.u.i.rgi[kk][bb][0]+S.u.i.rgi[kk][bb][1], RLX, AGENT);
          __hip_atomic_store(gh_pub + (k0+kk)*32 + bb,
                             S.u.i.rgh[kk][bb][0]+S.u.i.rgh[kk][bb][1], RLX, AGENT);
        }
      }
      DRAIN();
      __syncthreads();
      if(tid==0) __hip_atomic_store(flags + (224+ii)*16, (unsigned)(t+1), RLX, AGENT);
    }
  }
}

// ---------------- host ----------------
extern "C" void kernel_launch(void* const* d_in, const int* in_sizes, int n_in,
                              void* d_out, int out_size, void* d_ws, size_t ws_size,
                              hipStream_t stream)
{
  const float* up  = (const float*)d_in[0];
  const float* uq  = (const float*)d_in[1];
  const float* v0  = (const float*)d_in[2];
  const float* Vm  = (const float*)d_in[3];
  const float* Wp  = (const float*)d_in[4];
  const float* Wq  = (const float*)d_in[5];
  const float* Wv  = (const float*)d_in[6];
  const float* Wg  = (const float*)d_in[7];
  const float* W_ih= (const float*)d_in[8];
  const float* W_hh= (const float*)d_in[9];
  const float* b_ih= (const float*)d_in[10];
  const float* b_hh= (const float*)d_in[11];
  float* dout = (float*)d_out;
  char* wsb = (char*)d_ws;

  size_t off = 0;
  auto alloc = [&](size_t bytes)->size_t{ size_t p = off; off = (off + bytes + 255) & ~(size_t)255; return p; };
  size_t oWgupT = alloc((size_t)512*1024*4);     // 2MB; pubs+flags alias here after gemms
  size_t oWgcT  = alloc((size_t)512*1024*4);     // 2MB
  size_t oWuph  = alloc((size_t)32*512*152*2);   // 9.96MB
  size_t oWqUqh = alloc((size_t)32*256*152*2);   // 2.49MB
  size_t oWihP  = alloc((size_t)450*512*4);      // 0.92MB
  size_t oWhhP  = alloc((size_t)76*456*4);
  size_t oWvU   = alloc((size_t)76*152*4);
  size_t oUqP   = alloc((size_t)32*512*128*4);   // 8.39MB
  size_t oMp    = alloc((size_t)32*1024*128*4);  // 16.78MB
  size_t oGup2  = alloc((size_t)512*1024*32*2);  // 33.55MB; WpT/WqT alias (dead before write)
  if(ws_size < off) return;

  float*    WgupT = (float*)(wsb + oWgupT);
  float*    WgcT  = (float*)(wsb + oWgcT);
  _Float16* Wuph  = (_Float16*)(wsb + oWuph);
  _Float16* WqUqh = (_Float16*)(wsb + oWqUqh);
  unsigned* WihP  = (unsigned*)(wsb + oWihP);
  unsigned* WhhP  = (unsigned*)(wsb + oWhhP);
  unsigned* WvU   = (unsigned*)(wsb + oWvU);
  unsigned* uqP   = (unsigned*)(wsb + oUqP);
  unsigned* Mp    = (unsigned*)(wsb + oMp);
  _Float16* Gup2  = (_Float16*)(wsb + oGup2);
  float* WpT = (float*)(wsb + oGup2);            // dead before Gup2 written
  float* WqT = (float*)(wsb + oGup2 + 307456);

  // pubs + flags alias the (dead-after-gemms) WgupT region
  unsigned* a_pub  = (unsigned*)(wsb + oWgupT + 0);       // 16384B
  unsigned* v_pub  = (unsigned*)(wsb + oWgupT + 16384);   // 9728B
  unsigned* cc_pub = (unsigned*)(wsb + oWgupT + 26624);   // 32768B
  unsigned* g_pub  = (unsigned*)(wsb + oWgupT + 59392);   // 65536B
  float*    gi_pub = (float*)   (wsb + oWgupT + 124928);  // 61440B
  float*    gh_pub = (float*)   (wsb + oWgupT + 186368);  // 61440B
  unsigned* flags  = (unsigned*)(wsb + oWgupT + 247808);  // 16384B

  k_fold <<<256,256,0,stream>>>(Wp,Wq,Wg, WpT,WqT,WgupT,WgcT);
  k_fold2<<<256,256,0,stream>>>(W_ih, W_hh, Wv, WihP, WhhP, WvU);
  k_uqp  <<<dim3(32,8),256,0,stream>>>(uq, uqP);
  k_gemm<0><<<dim3(512,1),256,0,stream>>>(up, WpT, Wuph, 150);
  k_gemm<3><<<dim3(256,1),256,0,stream>>>(uq, WqT, WqUqh, 150);
  k_gemm<4><<<dim3(512,4),256,0,stream>>>(up, WgupT, Gup2, 1024);  // WpT/WqT dead now
  k_gemmM<<<dim3(32,8,4),256,0,stream>>>(uq, WgcT, Mp);
  k_init <<<4,1024,0,stream>>>(flags);                              // WgupT dead now

  int smem = (int)sizeof(SM);
  hipFuncSetAttribute((const void*)persist, hipFuncAttributeMaxDynamicSharedMemorySize, smem);
  void* ka[20] = { (void*)&uqP, (void*)&Mp, (void*)&Gup2, (void*)&Wuph, (void*)&WqUqh,
                   (void*)&WihP, (void*)&WhhP, (void*)&WvU, (void*)&v0, (void*)&Vm,
                   (void*)&b_ih, (void*)&b_hh,
                   (void*)&a_pub, (void*)&v_pub, (void*)&cc_pub, (void*)&g_pub,
                   (void*)&gi_pub, (void*)&gh_pub, (void*)&flags, (void*)&dout };
  hipLaunchCooperativeKernel((const void*)persist, dim3(254), dim3(1024), ka,
                             (unsigned)smem, stream);
}

// Round 7
// 14292.052 us; speedup vs baseline: 2.9792x; 1.0711x over previous
//
#include <hip/hip_runtime.h>
#include <hip/hip_bf16.h>

#define AGENT __HIP_MEMORY_SCOPE_AGENT
#define RLX __ATOMIC_RELAXED
typedef unsigned long long u64t;

typedef _Float16 h2 __attribute__((ext_vector_type(2)));
union U32H2 { unsigned u; h2 h; };
__device__ __forceinline__ h2 uh(unsigned u){ U32H2 c; c.u=u; return c.h; }
__device__ __forceinline__ unsigned pk(float a, float b){
  U32H2 c; c.h = h2{(_Float16)a, (_Float16)b}; return c.u;
}
#define RCPF(x) __builtin_amdgcn_rcpf(x)

__device__ __forceinline__ float DOT2(unsigned a, unsigned b, float acc){
#if __has_builtin(__builtin_amdgcn_fdot2)
  return __builtin_amdgcn_fdot2(uh(a), uh(b), acc, false);
#else
  h2 x = uh(a), y = uh(b);
  acc = fmaf((float)x[0], (float)y[0], acc);
  return fmaf((float)x[1], (float)y[1], acc);
#endif
}
__device__ __forceinline__ float sigm(float x){ return RCPF(1.0f+__expf(-x)); }
__device__ __forceinline__ float ftanh(float x){ return 1.0f - 2.0f*RCPF(1.0f+__expf(x+x)); }

// ---------- value-tagged pub/poll (relaxed 64-bit atomics only) ----------
__device__ __forceinline__ void pubw(u64t* p, unsigned seq, unsigned data){
  __hip_atomic_store(p, ((u64t)seq<<32)|(u64t)data, RLX, AGENT);
}
template<int K>
__device__ __forceinline__ void waitN(const u64t* base, const int* off, unsigned seq,
                                      unsigned* out, unsigned* kf){
  long n=0;
  for(;;){
    u64t v[K]; bool ok=true;
    #pragma unroll
    for(int k=0;k<K;k++) v[k]=__hip_atomic_load(base+off[k], RLX, AGENT);
    #pragma unroll
    for(int k=0;k<K;k++) ok &= ((unsigned)(v[k]>>32)==seq);
    if(ok){
      #pragma unroll
      for(int k=0;k<K;k++) out[k]=(unsigned)v[k];
      return;
    }
    __builtin_amdgcn_s_sleep(1);
    if((++n&255)==0){
      if(__hip_atomic_load(kf,RLX,AGENT)!=0u) break;
      if(n>300000L){ __hip_atomic_store(kf,1u,RLX,AGENT); break; }
    }
  }
  #pragma unroll
  for(int k=0;k<K;k++) out[k]=0u;
}
__device__ __forceinline__ void wait2p(const u64t* pa, const u64t* pb, unsigned seq,
                                       unsigned* oa, unsigned* ob, unsigned* kf){
  long n=0;
  for(;;){
    u64t va=__hip_atomic_load(pa,RLX,AGENT);
    u64t vb=__hip_atomic_load(pb,RLX,AGENT);
    if(((unsigned)(va>>32)==seq)&&((unsigned)(vb>>32)==seq)){ *oa=(unsigned)va; *ob=(unsigned)vb; return; }
    __builtin_amdgcn_s_sleep(1);
    if((++n&255)==0){
      if(__hip_atomic_load(kf,RLX,AGENT)!=0u) break;
      if(n>300000L){ __hip_atomic_store(kf,1u,RLX,AGENT); break; }
    }
  }
  *oa=0u; *ob=0u;
}

// ---------------- one-time weight folds (f32 GEMM inputs) ----------------
__global__ void k_fold(const float* __restrict__ Wp, const float* __restrict__ Wq,
                       const float* __restrict__ Wg,
                       float* __restrict__ WpT, float* __restrict__ WqT,
                       float* __restrict__ WgupT, float* __restrict__ WgcT)
{
  int i0 = blockIdx.x*blockDim.x+threadIdx.x;
  int st = gridDim.x*blockDim.x;
  for(int o=i0;o<512*150;o+=st){ int h=o%150, i=o/150;
    WpT[o]=Wp[h*1024+i]+Wp[h*1024+512+i];
    WqT[o]=Wq[h*1024+i]+Wq[h*1024+512+i]; }
  for(int o=i0;o<512*1024;o+=st){ int i=o&511, j=o>>9;
    size_t rb=(size_t)(1024+j)*2048;
    WgupT[(size_t)i*1024+j]=Wg[rb+i]+Wg[rb+512+i];
    WgcT [(size_t)i*1024+j]=Wg[rb+1024+i]+Wg[rb+1536+i]; }
}

// f16-pair layouts: WihP[k*512+jp], WhhP[p*456+k], WvU[p*152+h]
__global__ void k_fold2(const float* __restrict__ Wih,
                        const float* __restrict__ Whh, const float* __restrict__ Wv,
                        unsigned* __restrict__ WihP,
                        unsigned* __restrict__ WhhP, unsigned* __restrict__ WvU)
{
  int i0 = blockIdx.x*blockDim.x+threadIdx.x;
  int st = gridDim.x*blockDim.x;
  for(int o=i0;o<450*512;o+=st){ int jp=o&511, k=o>>9;
    WihP[o] = pk(Wih[(size_t)k*1024+2*jp], Wih[(size_t)k*1024+2*jp+1]); }
  for(int o=i0;o<76*456;o+=st){ int k=o%456, p=o/456;
    float x=0.f,y=0.f;
    if(k<450){ if(2*p<150) x=Whh[k*150+2*p]; if(2*p+1<150) y=Whh[k*150+2*p+1]; }
    WhhP[o]=pk(x,y); }
  for(int o=i0;o<76*152;o+=st){ int h=o%152, p=o/152;
    float x=0.f,y=0.f;
    if(h<150){ if(2*p<150) x=Wv[h*150+2*p]; if(2*p+1<150) y=Wv[h*150+2*p+1]; }
    WvU[o]=pk(x,y); }
}

// uq (q,b,i) f32 -> uqP[(b*512+i)*128 + qp] pairs over q
__global__ __launch_bounds__(256) void k_uqp(const float* __restrict__ uq, unsigned* __restrict__ uqP){
  __shared__ float Al[32*512];
  int b = blockIdx.x, qt = blockIdx.y, tid = threadIdx.x;
  for(int o4=tid;o4<4096;o4+=256){ int m=o4>>7, i4=o4&127;
    ((float4*)Al)[o4] = *(const float4*)&uq[(size_t)(qt*32+m)*16384 + b*512 + i4*4]; }
  __syncthreads();
  for(int o=tid;o<8192;o+=256){ int i=o>>4, p=o&15;
    uqP[((size_t)b*512+i)*128 + qt*16 + p] = pk(Al[(2*p)*512+i], Al[(2*p+1)*512+i]); }
}

// precompute GEMMs: MODE0 Wuph[b][t][152] ; MODE3 WqUqh[b][q][152] ; MODE4 Gup3[b][t][1024]
template<int MODE>
__global__ __launch_bounds__(256) void k_gemm(const float* __restrict__ A,
   const float* __restrict__ WT, _Float16* __restrict__ oH, int N)
{
  __shared__ float Al[32*512];
  int mt=blockIdx.x, nt=blockIdx.y, tid=threadIdx.x;
  const float* Ab = A + (size_t)mt*16384;
  for(int o=tid;o<4096;o+=256) ((float4*)Al)[o]=((const float4*)Ab)[o];
  __syncthreads();
  int n = nt*256+tid;
  if(n>=N) return;
  float acc[32];
  #pragma unroll
  for(int m=0;m<32;m++) acc[m]=0.f;
  const float* wp = WT + n;
  #pragma unroll 2
  for(int k=0;k<512;k+=2){
    float w0 = wp[(size_t)k*N], w1 = wp[(size_t)(k+1)*N];
    #pragma unroll
    for(int m=0;m<32;m++) acc[m]=fmaf(w0, Al[m*512+k], acc[m]);
    #pragma unroll
    for(int m=0;m<32;m++) acc[m]=fmaf(w1, Al[m*512+k+1], acc[m]);
  }
  if(MODE==0){
    #pragma unroll
    for(int m=0;m<32;m++) oH[((size_t)m*512 + mt)*152 + n] = (_Float16)acc[m];
  } else if(MODE==3){
    #pragma unroll
    for(int m=0;m<32;m++) oH[((size_t)m*256 + mt)*152 + n] = (_Float16)acc[m];
  } else {
    #pragma unroll
    for(int m=0;m<32;m++) oH[((size_t)m*512 + mt)*1024 + n] = (_Float16)acc[m];
  }
}

// M[b] = uq[b] @ WgcT : Mp[(b*1024+j)*128 + qp] = pk(M[2qp,j], M[2qp+1,j])
__global__ __launch_bounds__(256) void k_gemmM(const float* __restrict__ uq,
   const float* __restrict__ WgcT, unsigned* __restrict__ Mp)
{
  __shared__ float Al[32*512];
  int b=blockIdx.x, qt=blockIdx.y, nt=blockIdx.z, tid=threadIdx.x;
  for(int o4=tid;o4<4096;o4+=256){ int m=o4>>7, i4=o4&127;
    ((float4*)Al)[o4] = *(const float4*)&uq[(size_t)(qt*32+m)*16384 + b*512 + i4*4]; }
  __syncthreads();
  int n = nt*256+tid;
  float acc[32];
  #pragma unroll
  for(int m=0;m<32;m++) acc[m]=0.f;
  const float* wp = WgcT + n;
  #pragma unroll 2
  for(int k=0;k<512;k+=2){
    float w0 = wp[(size_t)k*1024], w1 = wp[(size_t)(k+1)*1024];
    #pragma unroll
    for(int m=0;m<32;m++) acc[m]=fmaf(w0, Al[m*512+k], acc[m]);
    #pragma unroll
    for(int m=0;m<32;m++) acc[m]=fmaf(w1, Al[m*512+k+1], acc[m]);
  }
  #pragma unroll
  for(int p=0;p<16;p++)
    Mp[((size_t)b*1024 + n)*128 + qt*16 + p] = pk(acc[2*p], acc[2*p+1]);
}

__global__ void k_init(unsigned* comm){
  int i = blockIdx.x*blockDim.x + threadIdx.x;
  if(i < 119812) comm[i] = 0u;
}

// ---------------- persistent: 254 blocks, tagged-word LLC protocol ----------------
struct __align__(16) SMO {
  unsigned WvU[76*152];
  unsigned WqUq[256*76];
  unsigned wup[80], vp[80];
  float V[152], v[152], w2[152], s[256], a[256];
  float gi[452], gh[452], bi[452], bh[452];
};
struct __align__(16) SMC2 {
  unsigned uq4[32768];
  unsigned al[4096];
  float red[8][32][4];
};
struct __align__(16) SMG2 {
  unsigned Mp[32768];
  unsigned al[4096];
  float red[8][32][4];
  float gt[8][32];
  unsigned gup[128];
};
struct __align__(16) SMI2 {
  unsigned cw[16384];
  unsigned Wih[15*512];
  unsigned Whh[76*16];
  unsigned vl[2432];
  float rgi[15][32][2], rgh[15][32][2];
};
union SMU2 { SMO o; SMC2 c; SMG2 g; SMI2 i; };

__global__ __launch_bounds__(1024) void persist(
  const unsigned* __restrict__ uqP,   const unsigned* __restrict__ Mp,
  const unsigned* __restrict__ Gup3u, const unsigned* __restrict__ Wuphu,
  const unsigned* __restrict__ WqUqhu, const unsigned* __restrict__ WihP,
  const unsigned* __restrict__ WhhP,  const unsigned* __restrict__ WvUg,
  const float* __restrict__ v0, const float* __restrict__ Vin,
  const float* __restrict__ bih, const float* __restrict__ bhh,
  u64t* aP, u64t* vP, u64t* ccP, u64t* gP, u64t* giP, u64t* ghP, unsigned* kf,
  float* __restrict__ dout)
{
  extern __shared__ char smraw[];
  SMU2& S = *reinterpret_cast<SMU2*>(smraw);
  const int tid = threadIdx.x;
  const int bid = blockIdx.x;

  if(bid < 32){
    // ================= OWNER (per b): GRU, w2, s, softmax -> aP =================
    const int b = bid;
    for(int o=tid;o<11552;o+=1024) S.o.WvU[o]=WvUg[o];
    for(int o=tid;o<19456;o+=1024){ int q=o/76,w=o%76;
      S.o.WqUq[o]=WqUqhu[((size_t)b*256+q)*76+w]; }
    for(int o=tid;o<152;o+=1024){
      S.o.V[o]=(o<150)?Vin[b*150+o]:0.f;
      S.o.v[o]=(o<150)?v0[b*150+o]:0.f; }
    for(int o=tid;o<452;o+=1024){
      S.o.bi[o]=(o<450)?bih[o]:0.f;
      S.o.bh[o]=(o<450)?bhh[o]:0.f; }
    __syncthreads();

    for(int t=0;t<512;++t){
      if(tid<76) S.o.wup[tid]=Wuphu[((size_t)b*512+t)*76+tid];
      if(t>0){
        if(tid<450){
          unsigned gu,hu;
          wait2p(giP+tid*32+b, ghP+tid*32+b, (unsigned)t, &gu,&hu, kf);
          S.o.gi[tid]=__uint_as_float(gu); S.o.gh[tid]=__uint_as_float(hu);
        }
        __syncthreads();
        if(tid<150){
          float rg=sigm(S.o.gi[tid]+S.o.bi[tid] + S.o.gh[tid]+S.o.bh[tid]);
          float zg=sigm(S.o.gi[150+tid]+S.o.bi[150+tid] + S.o.gh[150+tid]+S.o.bh[150+tid]);
          float ng=ftanh(S.o.gi[300+tid]+S.o.bi[300+tid] + rg*(S.o.gh[300+tid]+S.o.bh[300+tid]));
          float vn=fmaf(zg, S.o.v[tid]-ng, ng);
          S.o.v[tid]=vn;
          dout[((size_t)(t-1)*32+b)*150+tid]=vn;
        }
        __syncthreads();
      }
      if(tid<76){
        unsigned w = pk(S.o.v[2*tid], S.o.v[2*tid+1]);
        S.o.vp[tid]=w;
        pubw(vP+tid*32+b,(unsigned)(t+1),w);
      }
      __syncthreads();
      if(tid<608){
        int h=tid>>2, qd=tid&3;
        float acc=0.f;
        if(h<150){
          #pragma unroll
          for(int p=qd*19;p<qd*19+19;p++) acc=DOT2(S.o.WvU[p*152+h], S.o.vp[p], acc);
        }
        acc+=__shfl_xor(acc,1,64); acc+=__shfl_xor(acc,2,64);
        if(h<150&&qd==0){ h2 ww=uh(S.o.wup[h>>1]); S.o.w2[h]=acc+(float)ww[h&1]; }
      }
      __syncthreads();
      {
        int q=tid>>2, hq=tid&3;
        int hp0=hq*19, hp1=(hq==3)?75:hp0+19;
        float acc=0.f;
        for(int hp=hp0;hp<hp1;hp++){
          h2 wp=uh(S.o.WqUq[q*76+hp]);
          acc=fmaf(S.o.V[2*hp],   ftanh(S.o.w2[2*hp]  +(float)wp[0]), acc);
          acc=fmaf(S.o.V[2*hp+1], ftanh(S.o.w2[2*hp+1]+(float)wp[1]), acc);
        }
        acc+=__shfl_xor(acc,1,64); acc+=__shfl_xor(acc,2,64);
        if(hq==0) S.o.s[q]=acc;
      }
      __syncthreads();
      if(tid<64){
        float x0=S.o.s[tid],x1=S.o.s[tid+64],x2=S.o.s[tid+128],x3=S.o.s[tid+192];
        float mx=fmaxf(fmaxf(x0,x1),fmaxf(x2,x3));
        #pragma unroll
        for(int o=1;o<64;o<<=1) mx=fmaxf(mx,__shfl_xor(mx,o,64));
        float e0=__expf(x0-mx),e1=__expf(x1-mx),e2=__expf(x2-mx),e3=__expf(x3-mx);
        float sm=e0+e1+e2+e3;
        #pragma unroll
        for(int o=1;o<64;o<<=1) sm+=__shfl_xor(sm,o,64);
        float rs=RCPF(sm);
        S.o.a[tid]=e0*rs; S.o.a[tid+64]=e1*rs; S.o.a[tid+128]=e2*rs; S.o.a[tid+192]=e3*rs;
      }
      __syncthreads();
      if(tid<128) pubw(aP+tid*32+b,(unsigned)(t+1), pk(S.o.a[2*tid],S.o.a[2*tid+1]));
      __syncthreads();
    }
    // epilogue: v_512 -> dout[511]
    if(tid<450){
      unsigned gu,hu;
      wait2p(giP+tid*32+b, ghP+tid*32+b, 512u, &gu,&hu, kf);
      S.o.gi[tid]=__uint_as_float(gu); S.o.gh[tid]=__uint_as_float(hu);
    }
    __syncthreads();
    if(tid<150){
      float rg=sigm(S.o.gi[tid]+S.o.bi[tid] + S.o.gh[tid]+S.o.bh[tid]);
      float zg=sigm(S.o.gi[150+tid]+S.o.bi[150+tid] + S.o.gh[150+tid]+S.o.bh[150+tid]);
      float ng=ftanh(S.o.gi[300+tid]+S.o.bi[300+tid] + rg*(S.o.gh[300+tid]+S.o.bh[300+tid]));
      dout[((size_t)511*32+b)*150+tid]=fmaf(zg, S.o.v[tid]-ng, ng);
    }

  } else if(bid < 96){
    // ================= CC: cc i-slice of 8, all b =================
    const int ic = bid-32;
    for(int o=tid;o<32768;o+=1024){
      int qp=o&127, il=(o>>7)&7, bb=o>>10;
      S.c.uq4[qp*256 + il*32 + bb] = uqP[((size_t)bb*512 + ic*8+il)*128 + qp];
    }
    __syncthreads();
    for(int t=0;t<512;++t){
      {
        int off[4]={tid,tid+1024,tid+2048,tid+3072};
        unsigned av[4];
        waitN<4>(aP,off,(unsigned)(t+1),av,kf);
        S.c.al[tid]=av[0]; S.c.al[tid+1024]=av[1]; S.c.al[tid+2048]=av[2]; S.c.al[tid+3072]=av[3];
      }
      __syncthreads();
      {
        int bb=tid&31, il=(tid>>5)&7, qc=tid>>8;
        float acc=0.f;
        #pragma unroll 8
        for(int k=0;k<32;k++){
          int qp=qc*32+k;
          acc=DOT2(S.c.al[qp*32+bb], S.c.uq4[qp*256+il*32+bb], acc); }
        S.c.red[il][bb][qc]=acc;
      }
      __syncthreads();
      if(tid<128){
        int ip=tid>>5, bb=tid&31;
        float c0=S.c.red[2*ip][bb][0]+S.c.red[2*ip][bb][1]+S.c.red[2*ip][bb][2]+S.c.red[2*ip][bb][3];
        float c1=S.c.red[2*ip+1][bb][0]+S.c.red[2*ip+1][bb][1]+S.c.red[2*ip+1][bb][2]+S.c.red[2*ip+1][bb][3];
        pubw(ccP+((ic*4+ip)*32+bb),(unsigned)(t+1),pk(c0,c1));
      }
      __syncthreads();
    }

  } else if(bid < 224){
    // ================= G: Gc = a.M, gate -> gP (j-slice of 8, all b) =================
    const int jg = bid-96;
    const int j0 = jg*8;
    for(int o=tid;o<32768;o+=1024){
      int qp=o&127, jl=(o>>7)&7, bb=o>>10;
      S.g.Mp[qp*256 + jl*32 + bb] = Mp[((size_t)bb*1024 + j0+jl)*128 + qp];
    }
    __syncthreads();
    for(int t=0;t<512;++t){
      if(tid<128){ int bb=tid>>2, m=tid&3;
        S.g.gup[tid] = Gup3u[((size_t)bb*512+t)*512 + jg*4 + m]; }
      {
        int off[4]={tid,tid+1024,tid+2048,tid+3072};
        unsigned av[4];
        waitN<4>(aP,off,(unsigned)(t+1),av,kf);
        S.g.al[tid]=av[0]; S.g.al[tid+1024]=av[1]; S.g.al[tid+2048]=av[2]; S.g.al[tid+3072]=av[3];
      }
      __syncthreads();
      {
        int bb=tid&31, jl=(tid>>5)&7, qc=tid>>8;
        float acc=0.f;
        #pragma unroll 8
        for(int k=0;k<32;k++){
          int qp=qc*32+k;
          acc=DOT2(S.g.al[qp*32+bb], S.g.Mp[qp*256+jl*32+bb], acc); }
        S.g.red[jl][bb][qc]=acc;
      }
      __syncthreads();
      if(tid<256){
        int jl=tid>>5, bb=tid&31;
        float Gc=S.g.red[jl][bb][0]+S.g.red[jl][bb][1]+S.g.red[jl][bb][2]+S.g.red[jl][bb][3];
        h2 gv=uh(S.g.gup[bb*4+(jl>>1)]);
        S.g.gt[jl][bb]=sigm(Gc+(float)gv[jl&1]);
      }
      __syncthreads();
      if(tid<128){
        int jpl=tid>>5, bb=tid&31;
        pubw(gP+((jg*4+jpl)*32+bb),(unsigned)(t+1), pk(S.g.gt[2*jpl][bb],S.g.gt[2*jpl+1][bb]));
      }
      __syncthreads();
    }

  } else if(bid < 254){
    // ================= I: gh early, then gi = Wih.(g*cc)  (k-slice of 15) =================
    const int ii = bid-224;
    const int k0 = ii*15;
    for(int o=tid;o<7680;o+=1024){ int kk=o>>9, jp=o&511;
      S.i.Wih[kk*512+jp] = WihP[(size_t)(k0+kk)*512 + jp]; }
    for(int o=tid;o<1216;o+=1024){ int p=o>>4, kk=o&15;
      S.i.Whh[p*16+kk] = (kk<15)? WhhP[p*456 + k0+kk] : 0u; }
    __syncthreads();
    for(int t=0;t<512;++t){
      // v (tagged) -> gh partials -> publish ghP early
      {
        int off[3]; unsigned vv[3];
        off[0]=tid; off[1]=tid+1024; off[2]=(tid<384)?(tid+2048):tid;
        waitN<3>(vP,off,(unsigned)(t+1),vv,kf);
        S.i.vl[tid]=vv[0]; S.i.vl[tid+1024]=vv[1];
        if(tid<384) S.i.vl[tid+2048]=vv[2];
      }
      __syncthreads();
      {
        int bb=tid&31, kk=(tid>>5)&15, hh=tid>>9;
        if(kk<15){
          float ah=0.f;
          int p0=hh*38, p1=hh?76:38;
          for(int p=p0;p<p1;p++) ah=DOT2(S.i.Whh[p*16+kk], S.i.vl[p*32+bb], ah);
          S.i.rgh[kk][bb][hh]=ah;
        }
      }
      __syncthreads();
      if(tid<512){
        int kk=tid>>5, bb=tid&31;
        if(kk<15)
          pubw(ghP+((k0+kk)*32+bb),(unsigned)(t+1),
               __float_as_uint(S.i.rgh[kk][bb][0]+S.i.rgh[kk][bb][1]));
      }
      // g & cc (tagged), form c_ = g*cc
      {
        int offg[8]; unsigned gv0[8], gv1[8];
        #pragma unroll
        for(int k=0;k<8;k++) offg[k]=tid+1024*k;
        waitN<8>(gP,offg,(unsigned)(t+1),gv0,kf);
        #pragma unroll
        for(int k=0;k<8;k++) offg[k]=tid+1024*(k+8);
        waitN<8>(gP,offg,(unsigned)(t+1),gv1,kf);
        int offc[8]; unsigned cv[8];
        #pragma unroll
        for(int k=0;k<8;k++) offc[k]=(tid+1024*k)&8191;
        waitN<8>(ccP,offc,(unsigned)(t+1),cv,kf);
        #pragma unroll
        for(int k=0;k<8;k++){
          int o=tid+1024*k;
          h2 g2=uh(gv0[k]), c2=uh(cv[k]);
          S.i.cw[o]=pk((float)g2[0]*(float)c2[0],(float)g2[1]*(float)c2[1]);
        }
        #pragma unroll
        for(int k=0;k<8;k++){
          int o=tid+1024*(k+8);
          h2 g2=uh(gv1[k]), c2=uh(cv[k]);
          S.i.cw[o]=pk((float)g2[0]*(float)c2[0],(float)g2[1]*(float)c2[1]);
        }
      }
      __syncthreads();
      {
        int bb=tid&31, kk=(tid>>5)&15, hh=tid>>9;
        if(kk<15){
          float gi=0.f;
          const unsigned* wr=&S.i.Wih[kk*512];
          #pragma unroll 8
          for(int jp=hh*256; jp<hh*256+256; jp++)
            gi=DOT2(wr[jp], S.i.cw[jp*32+bb], gi);
          S.i.rgi[kk][bb][hh]=gi;
        }
      }
      __syncthreads();
      if(tid<512){
        int kk=tid>>5, bb=tid&31;
        if(kk<15)
          pubw(giP+((k0+kk)*32+bb),(unsigned)(t+1),
               __float_as_uint(S.i.rgi[kk][bb][0]+S.i.rgi[kk][bb][1]));
      }
      __syncthreads();
    }
  }
}

// ---------------- host ----------------
extern "C" void kernel_launch(void* const* d_in, const int* in_sizes, int n_in,
                              void* d_out, int out_size, void* d_ws, size_t ws_size,
                              hipStream_t stream)
{
  const float* up  = (const float*)d_in[0];
  const float* uq  = (const float*)d_in[1];
  const float* v0  = (const float*)d_in[2];
  const float* Vm  = (const float*)d_in[3];
  const float* Wp  = (const float*)d_in[4];
  const float* Wq  = (const float*)d_in[5];
  const float* Wv  = (const float*)d_in[6];
  const float* Wg  = (const float*)d_in[7];
  const float* W_ih= (const float*)d_in[8];
  const float* W_hh= (const float*)d_in[9];
  const float* b_ih= (const float*)d_in[10];
  const float* b_hh= (const float*)d_in[11];
  float* dout = (float*)d_out;
  char* wsb = (char*)d_ws;

  size_t off = 0;
  auto alloc = [&](size_t bytes)->size_t{ size_t p = off; off = (off + bytes + 255) & ~(size_t)255; return p; };
  size_t oWgupT = alloc((size_t)512*1024*4);      // 2MB; comm aliases after gemms
  size_t oWgcT  = alloc((size_t)512*1024*4);
  size_t oWuph  = alloc((size_t)32*512*152*2);
  size_t oWqUqh = alloc((size_t)32*256*152*2);
  size_t oWihP  = alloc((size_t)450*512*4);
  size_t oWhhP  = alloc((size_t)76*456*4);
  size_t oWvU   = alloc((size_t)76*152*4);
  size_t oUqP   = alloc((size_t)32*512*128*4);
  size_t oMp    = alloc((size_t)32*1024*128*4);
  size_t oGup3  = alloc((size_t)32*512*1024*2);   // WpT/WqT alias (dead before write)
  if(ws_size < off) return;

  float*    WgupT = (float*)(wsb + oWgupT);
  float*    WgcT  = (float*)(wsb + oWgcT);
  _Float16* Wuph  = (_Float16*)(wsb + oWuph);
  _Float16* WqUqh = (_Float16*)(wsb + oWqUqh);
  unsigned* WihP  = (unsigned*)(wsb + oWihP);
  unsigned* WhhP  = (unsigned*)(wsb + oWhhP);
  unsigned* WvU   = (unsigned*)(wsb + oWvU);
  unsigned* uqP   = (unsigned*)(wsb + oUqP);
  unsigned* Mp    = (unsigned*)(wsb + oMp);
  _Float16* Gup3  = (_Float16*)(wsb + oGup3);
  float* WpT = (float*)(wsb + oGup3);
  float* WqT = (float*)(wsb + oGup3 + 307456);

  // tagged pubs alias the (dead-after-gemms) WgupT region
  u64t* comm64 = (u64t*)(wsb + oWgupT);
  u64t* aP  = comm64;             // 4096
  u64t* vP  = comm64 + 4096;      // 2432
  u64t* ccP = comm64 + 6528;      // 8192
  u64t* gP  = comm64 + 14720;     // 16384
  u64t* giP = comm64 + 31104;     // 14400
  u64t* ghP = comm64 + 45504;     // 14400
  unsigned* kf = (unsigned*)(comm64 + 59904);

  k_fold <<<256,256,0,stream>>>(Wp,Wq,Wg, WpT,WqT,WgupT,WgcT);
  k_fold2<<<256,256,0,stream>>>(W_ih, W_hh, Wv, WihP, WhhP, WvU);
  k_uqp  <<<dim3(32,8),256,0,stream>>>(uq, uqP);
  k_gemm<0><<<dim3(512,1),256,0,stream>>>(up, WpT, Wuph, 150);
  k_gemm<3><<<dim3(256,1),256,0,stream>>>(uq, WqT, WqUqh, 150);
  k_gemm<4><<<dim3(512,4),256,0,stream>>>(up, WgupT, Gup3, 1024);  // WpT/WqT dead now
  k_gemmM<<<dim3(32,8,4),256,0,stream>>>(uq, WgcT, Mp);
  k_init <<<118,1024,0,stream>>>((unsigned*)comm64);                // WgupT dead now

  int smem = (int)sizeof(SMU2);
  hipFuncSetAttribute((const void*)persist, hipFuncAttributeMaxDynamicSharedMemorySize, smem);
  const unsigned* Gup3u  = (const unsigned*)Gup3;
  const unsigned* Wuphu  = (const unsigned*)Wuph;
  const unsigned* WqUqhu = (const unsigned*)WqUqh;
  void* ka[20] = { (void*)&uqP, (void*)&Mp, (void*)&Gup3u, (void*)&Wuphu, (void*)&WqUqhu,
                   (void*)&WihP, (void*)&WhhP, (void*)&WvU,
                   (void*)&v0, (void*)&Vm, (void*)&b_ih, (void*)&b_hh,
                   (void*)&aP, (void*)&vP, (void*)&ccP, (void*)&gP,
                   (void*)&giP, (void*)&ghP, (void*)&kf, (void*)&dout };
  hipLaunchCooperativeKernel((const void*)persist, dim3(254), dim3(1024), ka,
                             (unsigned)smem, stream);
}

// Round 8
// 7354.384 us; speedup vs baseline: 5.7897x; 1.9433x over previous
//
#include <hip/hip_runtime.h>
#include <hip/hip_bf16.h>

#define AGENT __HIP_MEMORY_SCOPE_AGENT
#define RLX __ATOMIC_RELAXED
typedef unsigned long long u64t;

typedef _Float16 h2 __attribute__((ext_vector_type(2)));
union U32H2 { unsigned u; h2 h; };
__device__ __forceinline__ h2 uh(unsigned u){ U32H2 c; c.u=u; return c.h; }
__device__ __forceinline__ unsigned pk(float a, float b){
  U32H2 c; c.h = h2{(_Float16)a, (_Float16)b}; return c.u;
}
#define RCPF(x) __builtin_amdgcn_rcpf(x)

__device__ __forceinline__ float DOT2(unsigned a, unsigned b, float acc){
#if __has_builtin(__builtin_amdgcn_fdot2)
  return __builtin_amdgcn_fdot2(uh(a), uh(b), acc, false);
#else
  h2 x = uh(a), y = uh(b);
  acc = fmaf((float)x[0], (float)y[0], acc);
  return fmaf((float)x[1], (float)y[1], acc);
#endif
}
__device__ __forceinline__ float sigm(float x){ return RCPF(1.0f+__expf(-x)); }
__device__ __forceinline__ float ftanh(float x){ return 1.0f - 2.0f*RCPF(1.0f+__expf(x+x)); }

// ---------- value-tagged pub/poll (relaxed 64-bit agent atomics; R7-proven) ----------
__device__ __forceinline__ void pubw(u64t* p, unsigned seq, unsigned data){
  __hip_atomic_store(p, ((u64t)seq<<32)|(u64t)data, RLX, AGENT);
}
template<int K>
__device__ __forceinline__ void waitN(const u64t* base, const int* off, unsigned seq,
                                      unsigned* out, unsigned* kf){
  long n=0;
  for(;;){
    u64t v[K]; bool ok=true;
    #pragma unroll
    for(int k=0;k<K;k++) v[k]=__hip_atomic_load(base+off[k], RLX, AGENT);
    #pragma unroll
    for(int k=0;k<K;k++) ok &= ((unsigned)(v[k]>>32)==seq);
    if(ok){
      #pragma unroll
      for(int k=0;k<K;k++) out[k]=(unsigned)v[k];
      return;
    }
    __builtin_amdgcn_s_sleep(1);
    if((++n&63)==0){
      if(__hip_atomic_load(kf,RLX,AGENT)!=0u) break;
      if(n>300000L){ __hip_atomic_store(kf,1u,RLX,AGENT); break; }
    }
  }
  #pragma unroll
  for(int k=0;k<K;k++) out[k]=0u;
}

// ---------------- one-time weight folds (f32 GEMM inputs) ----------------
__global__ void k_fold(const float* __restrict__ Wp, const float* __restrict__ Wq,
                       const float* __restrict__ Wg,
                       float* __restrict__ WpT, float* __restrict__ WqT,
                       float* __restrict__ WgupT, float* __restrict__ WgcT)
{
  int i0 = blockIdx.x*blockDim.x+threadIdx.x;
  int st = gridDim.x*blockDim.x;
  for(int o=i0;o<512*150;o+=st){ int h=o%150, i=o/150;
    WpT[o]=Wp[h*1024+i]+Wp[h*1024+512+i];
    WqT[o]=Wq[h*1024+i]+Wq[h*1024+512+i]; }
  for(int o=i0;o<512*1024;o+=st){ int i=o&511, j=o>>9;
    size_t rb=(size_t)(1024+j)*2048;
    WgupT[(size_t)i*1024+j]=Wg[rb+i]+Wg[rb+512+i];
    WgcT [(size_t)i*1024+j]=Wg[rb+1024+i]+Wg[rb+1536+i]; }
}

// pair layouts: WihT[jp*456+k] (transposed, coalesced in k), WhhP[p*456+k], WvU[p*152+h]
__global__ void k_fold2(const float* __restrict__ Wih,
                        const float* __restrict__ Whh, const float* __restrict__ Wv,
                        unsigned* __restrict__ WihT,
                        unsigned* __restrict__ WhhP, unsigned* __restrict__ WvU)
{
  int i0 = blockIdx.x*blockDim.x+threadIdx.x;
  int st = gridDim.x*blockDim.x;
  for(int o=i0;o<512*450;o+=st){ int k=o%450, jp=o/450;
    WihT[(size_t)jp*456+k] = pk(Wih[(size_t)k*1024+2*jp], Wih[(size_t)k*1024+2*jp+1]); }
  for(int o=i0;o<76*456;o+=st){ int k=o%456, p=o/456;
    float x=0.f,y=0.f;
    if(k<450){ if(2*p<150) x=Whh[k*150+2*p]; if(2*p+1<150) y=Whh[k*150+2*p+1]; }
    WhhP[o]=pk(x,y); }
  for(int o=i0;o<76*152;o+=st){ int h=o%152, p=o/152;
    float x=0.f,y=0.f;
    if(h<150){ if(2*p<150) x=Wv[h*150+2*p]; if(2*p+1<150) y=Wv[h*150+2*p+1]; }
    WvU[o]=pk(x,y); }
}

// uq (q,b,i) f32 -> uqP[(b*512+i)*128 + qp] pairs over q
__global__ __launch_bounds__(256) void k_uqp(const float* __restrict__ uq, unsigned* __restrict__ uqP){
  __shared__ float Al[32*512];
  int b = blockIdx.x, qt = blockIdx.y, tid = threadIdx.x;
  for(int o4=tid;o4<4096;o4+=256){ int m=o4>>7, i4=o4&127;
    ((float4*)Al)[o4] = *(const float4*)&uq[(size_t)(qt*32+m)*16384 + b*512 + i4*4]; }
  __syncthreads();
  for(int o=tid;o<8192;o+=256){ int i=o>>4, p=o&15;
    uqP[((size_t)b*512+i)*128 + qt*16 + p] = pk(Al[(2*p)*512+i], Al[(2*p+1)*512+i]); }
}

// precompute GEMMs: MODE0 Wuph[b][t][152] ; MODE3 WqUqh[b][q][152] ; MODE4 Gup3[b][t][1024]
template<int MODE>
__global__ __launch_bounds__(256) void k_gemm(const float* __restrict__ A,
   const float* __restrict__ WT, _Float16* __restrict__ oH, int N)
{
  __shared__ float Al[32*512];
  int mt=blockIdx.x, nt=blockIdx.y, tid=threadIdx.x;
  const float* Ab = A + (size_t)mt*16384;
  for(int o=tid;o<4096;o+=256) ((float4*)Al)[o]=((const float4*)Ab)[o];
  __syncthreads();
  int n = nt*256+tid;
  if(n>=N) return;
  float acc[32];
  #pragma unroll
  for(int m=0;m<32;m++) acc[m]=0.f;
  const float* wp = WT + n;
  #pragma unroll 2
  for(int k=0;k<512;k+=2){
    float w0 = wp[(size_t)k*N], w1 = wp[(size_t)(k+1)*N];
    #pragma unroll
    for(int m=0;m<32;m++) acc[m]=fmaf(w0, Al[m*512+k], acc[m]);
    #pragma unroll
    for(int m=0;m<32;m++) acc[m]=fmaf(w1, Al[m*512+k+1], acc[m]);
  }
  if(MODE==0){
    #pragma unroll
    for(int m=0;m<32;m++) oH[((size_t)m*512 + mt)*152 + n] = (_Float16)acc[m];
  } else if(MODE==3){
    #pragma unroll
    for(int m=0;m<32;m++) oH[((size_t)m*256 + mt)*152 + n] = (_Float16)acc[m];
  } else {
    #pragma unroll
    for(int m=0;m<32;m++) oH[((size_t)m*512 + mt)*1024 + n] = (_Float16)acc[m];
  }
}

// M[b] = uq[b] @ WgcT : Mp[(b*1024+j)*128 + qp] = pk(M[2qp,j], M[2qp+1,j])
__global__ __launch_bounds__(256) void k_gemmM(const float* __restrict__ uq,
   const float* __restrict__ WgcT, unsigned* __restrict__ Mp)
{
  __shared__ float Al[32*512];
  int b=blockIdx.x, qt=blockIdx.y, nt=blockIdx.z, tid=threadIdx.x;
  for(int o4=tid;o4<4096;o4+=256){ int m=o4>>7, i4=o4&127;
    ((float4*)Al)[o4] = *(const float4*)&uq[(size_t)(qt*32+m)*16384 + b*512 + i4*4]; }
  __syncthreads();
  int n = nt*256+tid;
  float acc[32];
  #pragma unroll
  for(int m=0;m<32;m++) acc[m]=0.f;
  const float* wp = WgcT + n;
  #pragma unroll 2
  for(int k=0;k<512;k+=2){
    float w0 = wp[(size_t)k*1024], w1 = wp[(size_t)(k+1)*1024];
    #pragma unroll
    for(int m=0;m<32;m++) acc[m]=fmaf(w0, Al[m*512+k], acc[m]);
    #pragma unroll
    for(int m=0;m<32;m++) acc[m]=fmaf(w1, Al[m*512+k+1], acc[m]);
  }
  #pragma unroll
  for(int p=0;p<16;p++)
    Mp[((size_t)b*1024 + n)*128 + qt*16 + p] = pk(acc[2*p], acc[2*p+1]);
}

__global__ void k_init(unsigned* comm){
  int i = blockIdx.x*blockDim.x + threadIdx.x;
  if(i < 123920) comm[i] = 0u;
}

// ---------------- persistent: 160 blocks, 2-hop per-batch pipelines ----------------
struct __align__(16) SMO {
  unsigned WvU[76*152];        // 46.2KB
  unsigned WqUq[256*76];       // 77.8KB
  unsigned wup[80], vp[80];
  float V[152], v[152], w2[152], s[256], a[256];
  float gi[452], rgh[2][452], bi[452], bh[452];
};
struct __align__(16) SMW {
  unsigned M[128*257];         // 131.6KB, [qp][jl] stride 257 (bank-tuned)
  unsigned a2[128], gup[128], cpr[128];
  float ccf[128], Gc[256], c_f[256], rgi[2][452];
};
union SMU { SMO o; SMW w; };

__global__ __launch_bounds__(1024) void persist(
  const unsigned* __restrict__ uqP,   const unsigned* __restrict__ Mp,
  const unsigned* __restrict__ Gup3u, const unsigned* __restrict__ Wuphu,
  const unsigned* __restrict__ WqUqhu, const unsigned* __restrict__ WihTu,
  const unsigned* __restrict__ WhhP,  const unsigned* __restrict__ WvUg,
  const float* __restrict__ v0, const float* __restrict__ Vin,
  const float* __restrict__ bih, const float* __restrict__ bhh,
  u64t* aP, u64t* giP, unsigned* kf,
  float* __restrict__ dout)
{
  extern __shared__ char smraw[];
  SMU& S = *reinterpret_cast<SMU*>(smraw);
  const int tid = threadIdx.x;
  const int bid = blockIdx.x;

  if(bid < 32){
    // ================= OWNER (per b): GRU + gh, w2, s, softmax -> aP =================
    const int b = bid;
    for(int o=tid;o<11552;o+=1024) S.o.WvU[o]=WvUg[o];
    for(int o=tid;o<19456;o+=1024){ int q=o/76,w=o%76;
      S.o.WqUq[o]=WqUqhu[((size_t)b*256+q)*76+w]; }
    for(int o=tid;o<152;o+=1024){
      S.o.V[o]=(o<150)?Vin[b*150+o]:0.f;
      S.o.v[o]=(o<150)?v0[b*150+o]:0.f; }
    for(int o=tid;o<452;o+=1024){
      S.o.bi[o]=(o<450)?bih[o]:0.f;
      S.o.bh[o]=(o<450)?bhh[o]:0.f; }
    __syncthreads();

    const int gibase = b*1808;   // b*4*452
    for(int t=0;t<512;++t){
      if(tid<76) S.o.wup[tid]=Wuphu[((size_t)b*512+t)*76+tid];
      if(t>0){
        if(tid<450){
          int off[4]={gibase+tid, gibase+452+tid, gibase+904+tid, gibase+1356+tid};
          unsigned gv[4];
          waitN<4>(giP,off,(unsigned)t,gv,kf);
          S.o.gi[tid]=__uint_as_float(gv[0])+__uint_as_float(gv[1])
                     +__uint_as_float(gv[2])+__uint_as_float(gv[3]);
        }
        __syncthreads();
        if(tid<150){
          float gh0=S.o.rgh[0][tid]+S.o.rgh[1][tid]+S.o.bh[tid];
          float gh1=S.o.rgh[0][150+tid]+S.o.rgh[1][150+tid]+S.o.bh[150+tid];
          float gh2=S.o.rgh[0][300+tid]+S.o.rgh[1][300+tid]+S.o.bh[300+tid];
          float rg=sigm(S.o.gi[tid]+S.o.bi[tid] + gh0);
          float zg=sigm(S.o.gi[150+tid]+S.o.bi[150+tid] + gh1);
          float ng=ftanh(S.o.gi[300+tid]+S.o.bi[300+tid] + rg*gh2);
          float vn=fmaf(zg, S.o.v[tid]-ng, ng);
          S.o.v[tid]=vn;
          dout[((size_t)(t-1)*32+b)*150+tid]=vn;
        }
        __syncthreads();
      }
      if(tid<76) S.o.vp[tid]=pk(S.o.v[2*tid], S.o.v[2*tid+1]);
      __syncthreads();
      // w2 = wup + Wv.v
      if(tid<608){
        int h=tid>>2, qd=tid&3;
        float acc=0.f;
        if(h<150){
          #pragma unroll
          for(int p=qd*19;p<qd*19+19;p++) acc=DOT2(S.o.WvU[p*152+h], S.o.vp[p], acc);
        }
        acc+=__shfl_xor(acc,1,64); acc+=__shfl_xor(acc,2,64);
        if(h<150&&qd==0){ h2 ww=uh(S.o.wup[h>>1]); S.o.w2[h]=acc+(float)ww[h&1]; }
      }
      __syncthreads();
      // s[q] = sum_h V[h] tanh(w2[h]+WqUq[q,h])
      {
        int q=tid>>2, hq=tid&3;
        int hp0=hq*19, hp1=(hq==3)?75:hp0+19;
        float acc=0.f;
        for(int hp=hp0;hp<hp1;hp++){
          h2 wp=uh(S.o.WqUq[q*76+hp]);
          acc=fmaf(S.o.V[2*hp],   ftanh(S.o.w2[2*hp]  +(float)wp[0]), acc);
          acc=fmaf(S.o.V[2*hp+1], ftanh(S.o.w2[2*hp+1]+(float)wp[1]), acc);
        }
        acc+=__shfl_xor(acc,1,64); acc+=__shfl_xor(acc,2,64);
        if(hq==0) S.o.s[q]=acc;
      }
      __syncthreads();
      if(tid<64){
        float x0=S.o.s[tid],x1=S.o.s[tid+64],x2=S.o.s[tid+128],x3=S.o.s[tid+192];
        float mx=fmaxf(fmaxf(x0,x1),fmaxf(x2,x3));
        #pragma unroll
        for(int o=1;o<64;o<<=1) mx=fmaxf(mx,__shfl_xor(mx,o,64));
        float e0=__expf(x0-mx),e1=__expf(x1-mx),e2=__expf(x2-mx),e3=__expf(x3-mx);
        float sm=e0+e1+e2+e3;
        #pragma unroll
        for(int o=1;o<64;o<<=1) sm+=__shfl_xor(sm,o,64);
        float rs=RCPF(sm);
        S.o.a[tid]=e0*rs; S.o.a[tid+64]=e1*rs; S.o.a[tid+128]=e2*rs; S.o.a[tid+192]=e3*rs;
      }
      __syncthreads();
      if(tid<128) pubw(aP+b*128+tid,(unsigned)(t+1), pk(S.o.a[2*tid],S.o.a[2*tid+1]));
      // gh = Whh.v  (overlaps with worker phase; consumed at next GRU)
      {
        int k=tid&511, half=tid>>9;
        float ah=0.f;
        if(k<450){
          int p0=half*38, p1=half?76:38;
          for(int p=p0;p<p1;p++) ah=DOT2(WhhP[p*456+k], S.o.vp[p], ah);
          S.o.rgh[half][k]=ah;
        }
      }
      // no sync needed here: rgh read only after next iteration's post-poll sync
    }
    // epilogue: v_512 -> dout[511]
    if(tid<450){
      int off[4]={gibase+tid, gibase+452+tid, gibase+904+tid, gibase+1356+tid};
      unsigned gv[4];
      waitN<4>(giP,off,512u,gv,kf);
      S.o.gi[tid]=__uint_as_float(gv[0])+__uint_as_float(gv[1])
                 +__uint_as_float(gv[2])+__uint_as_float(gv[3]);
    }
    __syncthreads();
    if(tid<150){
      float gh0=S.o.rgh[0][tid]+S.o.rgh[1][tid]+S.o.bh[tid];
      float gh1=S.o.rgh[0][150+tid]+S.o.rgh[1][150+tid]+S.o.bh[150+tid];
      float gh2=S.o.rgh[0][300+tid]+S.o.rgh[1][300+tid]+S.o.bh[300+tid];
      float rg=sigm(S.o.gi[tid]+S.o.bi[tid] + gh0);
      float zg=sigm(S.o.gi[150+tid]+S.o.bi[150+tid] + gh1);
      float ng=ftanh(S.o.gi[300+tid]+S.o.bi[300+tid] + rg*gh2);
      dout[((size_t)511*32+b)*150+tid]=fmaf(zg, S.o.v[tid]-ng, ng);
    }

  } else {
    // ================= WORKER (4 per b): cc, Gc=a.M, gate, c_, partial gi =================
    const int wid = bid-32;
    const int b = wid>>2, s = wid&3;
    // prologue: M j-slices {s, s+4} into LDS [qp][jl], stride 257
    for(int o=tid;o<32768;o+=1024){
      int qp=o&127, jl=o>>7;
      int j = s*128 + (jl&127) + ((jl>>7)<<9);     // s*128+(jl%128) + (jl>=128?512:0)
      S.w.M[qp*257+jl] = Mp[((size_t)b*1024+j)*128+qp];
    }
    __syncthreads();
    const size_t uqbase = ((size_t)b*512 + s*128)*128;
    for(int t=0;t<512;++t){
      if(tid<128){
        int wi = (tid<64)? (s*64+tid) : (256+s*64+tid-64);
        S.w.gup[tid] = Gup3u[((size_t)b*512+t)*512 + wi];
      }
      if(tid<128){
        int off[1]={b*128+tid};
        unsigned av[1];
        waitN<1>(aP,off,(unsigned)(t+1),av,kf);
        S.w.a2[tid]=av[0];
      }
      __syncthreads();
      // cc[i] = sum_qp dot2(a2, uq[i])   (uq slice streamed from L2)
      {
        int i=tid>>3, q8=tid&7;
        float acc=0.f;
        const unsigned* up = uqP + uqbase + (size_t)i*128;
        #pragma unroll 4
        for(int kk=0;kk<16;kk++){
          int qp=kk*8+q8;
          acc=DOT2(S.w.a2[qp], up[qp], acc);
        }
        acc+=__shfl_xor(acc,1,64); acc+=__shfl_xor(acc,2,64); acc+=__shfl_xor(acc,4,64);
        if(q8==0) S.w.ccf[i]=acc;
      }
      // Gc[jl] = sum_qp dot2(a2, M[qp][jl])
      {
        int jl=tid>>2, qc=tid&3;
        float acc=0.f;
        #pragma unroll 8
        for(int kk=0;kk<32;kk++){
          int qp=kk*4+qc;
          acc=DOT2(S.w.a2[qp], S.w.M[qp*257+jl], acc);
        }
        acc+=__shfl_xor(acc,1,64); acc+=__shfl_xor(acc,2,64);
        if(qc==0) S.w.Gc[jl]=acc;
      }
      __syncthreads();
      // c_[jl] = sigm(Gc+gup)*cc[jl&127]
      if(tid<256){
        h2 gv=uh(S.w.gup[tid>>1]);
        float g=sigm(S.w.Gc[tid]+(float)gv[tid&1]);
        S.w.c_f[tid]=g*S.w.ccf[tid&127];
      }
      __syncthreads();
      if(tid<128) S.w.cpr[tid]=pk(S.w.c_f[2*tid],S.w.c_f[2*tid+1]);
      __syncthreads();
      // partial gi[k] over this worker's 128 jp (WihT streamed, coalesced in k)
      {
        int k=tid&511, half=tid>>9;
        float acc=0.f;
        if(k<450){
          #pragma unroll 4
          for(int m=0;m<64;m++){
            int jpg = half*256 + s*64 + m;
            acc=DOT2(WihTu[(size_t)jpg*456+k], S.w.cpr[half*64+m], acc);
          }
          S.w.rgi[half][k]=acc;
        }
      }
      __syncthreads();
      if(tid<450)
        pubw(giP + ((size_t)b*4+s)*452 + tid, (unsigned)(t+1),
             __float_as_uint(S.w.rgi[0][tid]+S.w.rgi[1][tid]));
    }
  }
}

// ---------------- host ----------------
extern "C" void kernel_launch(void* const* d_in, const int* in_sizes, int n_in,
                              void* d_out, int out_size, void* d_ws, size_t ws_size,
                              hipStream_t stream)
{
  const float* up  = (const float*)d_in[0];
  const float* uq  = (const float*)d_in[1];
  const float* v0  = (const float*)d_in[2];
  const float* Vm  = (const float*)d_in[3];
  const float* Wp  = (const float*)d_in[4];
  const float* Wq  = (const float*)d_in[5];
  const float* Wv  = (const float*)d_in[6];
  const float* Wg  = (const float*)d_in[7];
  const float* W_ih= (const float*)d_in[8];
  const float* W_hh= (const float*)d_in[9];
  const float* b_ih= (const float*)d_in[10];
  const float* b_hh= (const float*)d_in[11];
  float* dout = (float*)d_out;
  char* wsb = (char*)d_ws;

  size_t off = 0;
  auto alloc = [&](size_t bytes)->size_t{ size_t p = off; off = (off + bytes + 255) & ~(size_t)255; return p; };
  size_t oWgupT = alloc((size_t)512*1024*4);      // 2MB; comm aliases after gemms
  size_t oWgcT  = alloc((size_t)512*1024*4);
  size_t oWuph  = alloc((size_t)32*512*152*2);
  size_t oWqUqh = alloc((size_t)32*256*152*2);
  size_t oWihT  = alloc((size_t)512*456*4);
  size_t oWhhP  = alloc((size_t)76*456*4);
  size_t oWvU   = alloc((size_t)76*152*4);
  size_t oUqP   = alloc((size_t)32*512*128*4);
  size_t oMp    = alloc((size_t)32*1024*128*4);
  size_t oGup3  = alloc((size_t)32*512*1024*2);   // WpT/WqT alias (dead before write)
  if(ws_size < off) return;

  float*    WgupT = (float*)(wsb + oWgupT);
  float*    WgcT  = (float*)(wsb + oWgcT);
  _Float16* Wuph  = (_Float16*)(wsb + oWuph);
  _Float16* WqUqh = (_Float16*)(wsb + oWqUqh);
  unsigned* WihT  = (unsigned*)(wsb + oWihT);
  unsigned* WhhP  = (unsigned*)(wsb + oWhhP);
  unsigned* WvU   = (unsigned*)(wsb + oWvU);
  unsigned* uqP   = (unsigned*)(wsb + oUqP);
  unsigned* Mp    = (unsigned*)(wsb + oMp);
  _Float16* Gup3  = (_Float16*)(wsb + oGup3);
  float* WpT = (float*)(wsb + oGup3);
  float* WqT = (float*)(wsb + oGup3 + 307456);

  // tagged pubs alias the (dead-after-gemms) WgupT region
  u64t* comm64 = (u64t*)(wsb + oWgupT);
  u64t* aP  = comm64;              // 32*128 = 4096
  u64t* giP = comm64 + 4096;       // 32*4*452 = 57856
  unsigned* kf = (unsigned*)(comm64 + 61952);

  k_fold <<<256,256,0,stream>>>(Wp,Wq,Wg, WpT,WqT,WgupT,WgcT);
  k_fold2<<<256,256,0,stream>>>(W_ih, W_hh, Wv, WihT, WhhP, WvU);
  k_uqp  <<<dim3(32,8),256,0,stream>>>(uq, uqP);
  k_gemm<0><<<dim3(512,1),256,0,stream>>>(up, WpT, Wuph, 150);
  k_gemm<3><<<dim3(256,1),256,0,stream>>>(uq, WqT, WqUqh, 150);
  k_gemm<4><<<dim3(512,4),256,0,stream>>>(up, WgupT, Gup3, 1024);  // WpT/WqT dead now
  k_gemmM<<<dim3(32,8,4),256,0,stream>>>(uq, WgcT, Mp);
  k_init <<<122,1024,0,stream>>>((unsigned*)comm64);                // WgupT dead now

  int smem = (int)sizeof(SMU);
  hipFuncSetAttribute((const void*)persist, hipFuncAttributeMaxDynamicSharedMemorySize, smem);
  const unsigned* Gup3u  = (const unsigned*)Gup3;
  const unsigned* Wuphu  = (const unsigned*)Wuph;
  const unsigned* WqUqhu = (const unsigned*)WqUqh;
  void* ka[16] = { (void*)&uqP, (void*)&Mp, (void*)&Gup3u, (void*)&Wuphu, (void*)&WqUqhu,
                   (void*)&WihT, (void*)&WhhP, (void*)&WvU,
                   (void*)&v0, (void*)&Vm, (void*)&b_ih, (void*)&b_hh,
                   (void*)&aP, (void*)&giP, (void*)&kf, (void*)&dout };
  hipLaunchCooperativeKernel((const void*)persist, dim3(160), dim3(1024), ka,
                             (unsigned)smem, stream);
}